// Round 16
// baseline (275.463 us; speedup 1.0000x reference)
//
#include <hip/hip_runtime.h>
#include <hip/hip_bf16.h>

typedef __attribute__((ext_vector_type(8))) short bf16x8;
typedef __attribute__((ext_vector_type(4))) float f32x4;
typedef unsigned short u16;

#define S_LEN 4096
#define DM 1024
#define NH 16
#define DH 64

// manual RNE fp32->bf16 (inputs never NaN here): 3 VALU ops
__device__ __forceinline__ u16 f2b_rne(float f) {
  unsigned u = __builtin_bit_cast(unsigned, f);
  return (u16)((u + 0x7fffu + ((u >> 16) & 1u)) >> 16);
}
// pack two fp32 -> bf16x2 in one u32 (RNE)
__device__ __forceinline__ unsigned pk2(float a, float b) {
  unsigned ua = __builtin_bit_cast(unsigned, a);
  unsigned ub = __builtin_bit_cast(unsigned, b);
  ua = (ua + 0x7fffu + ((ua >> 16) & 1u)) >> 16;
  ub = (ub + 0x7fffu + ((ub >> 16) & 1u)) & 0xffff0000u;
  return ua | ub;
}
// pack two fp32 -> bf16x2, TRUNCATED: single v_perm_b32 (low=a, high=b).
// bias cancels in softmax (same P in numerator and denominator).
__device__ __forceinline__ unsigned pk2t(float a, float b) {
  return __builtin_amdgcn_perm(__builtin_bit_cast(unsigned, b),
                               __builtin_bit_cast(unsigned, a), 0x07060302u);
}
// bf16 (u16) -> f32
__device__ __forceinline__ float b2f(unsigned u) {
  return __builtin_bit_cast(float, u << 16);
}

// global -> LDS direct (16B per lane; lds base must be wave-uniform)
__device__ __forceinline__ void glds16(const u16* g, u16* l) {
  __builtin_amdgcn_global_load_lds(
      (const __attribute__((address_space(1))) unsigned int*)g,
      (__attribute__((address_space(3))) unsigned int*)l, 16, 0, 0);
}

// ---------------- fp32 -> bf16, all 5 inputs in one launch ----------------
__global__ __launch_bounds__(256) void cvt_all(const float* __restrict__ x,
                                               const float* __restrict__ Wq,
                                               const float* __restrict__ Wk,
                                               const float* __restrict__ Wv,
                                               const float* __restrict__ Wo,
                                               u16* __restrict__ xb, u16* __restrict__ wqb,
                                               u16* __restrict__ wkb, u16* __restrict__ wvb,
                                               u16* __restrict__ wob) {
  int idx = (blockIdx.x * 256 + threadIdx.x) * 4;
  const float* src;
  u16* dst;
  int o;
  if (idx < 4194304) {
    src = x; dst = xb; o = idx;
  } else {
    int t = idx - 4194304;
    int wsel = t >> 20;
    o = t & 1048575;
    src = (wsel == 0) ? Wq : (wsel == 1) ? Wk : (wsel == 2) ? Wv : Wo;
    dst = (wsel == 0) ? wqb : (wsel == 1) ? wkb : (wsel == 2) ? wvb : wob;
  }
  float4 v = *(const float4*)(src + o);
  uint2 ov;
  ov.x = pk2(v.x, v.y);
  ov.y = pk2(v.z, v.w);
  *(uint2*)(dst + o) = ov;
}

// ---------------- zero the O/L accumulators (fallback path only) -----------
__global__ __launch_bounds__(256) void zero_kernel(float4* __restrict__ p) {
  p[blockIdx.x * 256 + threadIdx.x] = float4{0.f, 0.f, 0.f, 0.f};
}

// ---------------- fused QKV NT-GEMM with RoPE epilogue; V written transposed
// grid (24, 32): mat = bx>>3 (0=Q rope+scale, 1=K rope, 2=V -> Vt), nb = (bx&7)*128
__global__ __launch_bounds__(256) void qkv_gemm(const u16* __restrict__ A,
                                                const u16* __restrict__ Wq,
                                                const u16* __restrict__ Wk,
                                                const u16* __restrict__ Wv,
                                                u16* __restrict__ Qo, u16* __restrict__ Ko,
                                                u16* __restrict__ Vt) {
  __shared__ __align__(16) u16 As[2 * 128 * 32];
  __shared__ __align__(16) u16 Bs[2 * 128 * 32];
  const int mat = blockIdx.x >> 3;
  const u16* B = (mat == 0) ? Wq : (mat == 1) ? Wk : Wv;
  const int K = DM, N = DM;
  const int tid = threadIdx.x;
  const int wave = tid >> 6, lane = tid & 63;
  const int fm = lane & 15, fq = lane >> 4;
  const int mb = blockIdx.y * 128, nb = (blockIdx.x & 7) * 128;
  const int wm = (wave & 1) * 64, wn = (wave >> 1) * 64;

  f32x4 acc[4][4];
#pragma unroll
  for (int i = 0; i < 4; ++i)
#pragma unroll
    for (int j = 0; j < 4; ++j)
#pragma unroll
      for (int r = 0; r < 4; ++r) acc[i][j][r] = 0.f;

  const int r_ = tid >> 2;
  const int cg = (tid & 3) ^ ((r_ >> 1) & 3);
  const u16* Ag0 = A + (size_t)(mb + r_) * K + cg * 8;
  const u16* Ag1 = A + (size_t)(mb + r_ + 64) * K + cg * 8;
  const u16* Bg0 = B + (size_t)(nb + r_) * K + cg * 8;
  const u16* Bg1 = B + (size_t)(nb + r_ + 64) * K + cg * 8;
  const int l0 = wave * 512;
  const int l1 = 2048 + wave * 512;
  const int sw = (fm >> 1) & 3;

  int buf = 0;
  glds16(Ag0, As + l0);
  glds16(Ag1, As + l1);
  glds16(Bg0, Bs + l0);
  glds16(Bg1, Bs + l1);

  for (int k0 = 0; k0 < K; k0 += 32) {
    __syncthreads();
    if (k0 + 32 < K) {
      int bo = (buf ^ 1) * 4096;
      glds16(Ag0 + k0 + 32, As + bo + l0);
      glds16(Ag1 + k0 + 32, As + bo + l1);
      glds16(Bg0 + k0 + 32, Bs + bo + l0);
      glds16(Bg1 + k0 + 32, Bs + bo + l1);
    }
    const u16* Ab = As + buf * 4096;
    const u16* Bb = Bs + buf * 4096;
    bf16x8 av[4], bv[4];
#pragma unroll
    for (int t = 0; t < 4; ++t) {
      av[t] = *(const bf16x8*)(Ab + (wm + t * 16 + fm) * 32 + ((fq ^ sw) * 8));
      bv[t] = *(const bf16x8*)(Bb + (wn + t * 16 + fm) * 32 + ((fq ^ sw) * 8));
    }
#pragma unroll
    for (int i = 0; i < 4; ++i)
#pragma unroll
      for (int j = 0; j < 4; ++j)
        acc[i][j] = __builtin_amdgcn_mfma_f32_16x16x32_bf16(av[i], bv[j], acc[i][j], 0, 0, 0);
    buf ^= 1;
  }

  if (mat < 2) {
    // RoPE epilogue (in-register): pairs (d, d+32) = regs (j, j+2), d = j*16+fm, j in {0,1}
    u16* Out = (mat == 0) ? Qo : Ko;
    const float qs = (mat == 0) ? 0.1803368801111204f : 1.0f;  // 0.125*log2(e) for Q
    const float c1 = -9.2103403719761836f / 32.f;              // -ln(10000)/32
    const float if0 = __expf((float)fm * c1);
    const float if1 = __expf((float)(16 + fm) * c1);
#pragma unroll
    for (int ii = 0; ii < 4; ++ii) {
#pragma unroll
      for (int r = 0; r < 4; ++r) {
        float s = (float)(mb + wm + ii * 16 + fq * 4 + r);
#pragma unroll
        for (int jp = 0; jp < 2; ++jp) {
          float ang = s * (jp ? if1 : if0);
          float sn, cs;
          __sincosf(ang, &sn, &cs);
          float a = acc[ii][jp][r], b = acc[ii][jp + 2][r];
          acc[ii][jp][r] = (a * cs - b * sn) * qs;
          acc[ii][jp + 2][r] = (b * cs + a * sn) * qs;
        }
      }
    }
#pragma unroll
    for (int i = 0; i < 4; ++i)
#pragma unroll
      for (int j = 0; j < 4; ++j)
#pragma unroll
        for (int r = 0; r < 4; ++r) {
          int row = mb + wm + i * 16 + fq * 4 + r;
          int col = nb + wn + j * 16 + fm;
          Out[(size_t)row * N + col] = f2b_rne(acc[i][j][r]);
        }
  } else {
    // V: write transposed Vt[col][row]; 4 r-values are contiguous rows -> 8B store
#pragma unroll
    for (int i = 0; i < 4; ++i)
#pragma unroll
      for (int j = 0; j < 4; ++j) {
        int col = nb + wn + j * 16 + fm;
        int row0 = mb + wm + i * 16 + fq * 4;
        uint2 pv;
        pv.x = pk2(acc[i][j][0], acc[i][j][1]);
        pv.y = pk2(acc[i][j][2], acc[i][j][3]);
        *(uint2*)(Vt + (size_t)col * S_LEN + row0) = pv;
      }
  }
}

// ---------------- O-projection NT GEMM, 64x128 tiles (fp32 out) -------------
// grid (8, 64): nb = bx*128, mb = by*64. 512 blocks -> real occupancy (vs 256).
__global__ __launch_bounds__(256) void o_gemm(const u16* __restrict__ A,
                                              const u16* __restrict__ B,
                                              float* __restrict__ C, int M, int N, int K) {
  __shared__ __align__(16) u16 As[2 * 64 * 32];
  __shared__ __align__(16) u16 Bs[2 * 128 * 32];
  const int tid = threadIdx.x;
  const int wave = tid >> 6, lane = tid & 63;
  const int fm = lane & 15, fq = lane >> 4;
  const int mb = blockIdx.y * 64, nb = blockIdx.x * 128;
  const int wm = (wave & 1) * 32, wn = (wave >> 1) * 64;

  f32x4 acc[2][4];
#pragma unroll
  for (int i = 0; i < 2; ++i)
#pragma unroll
    for (int j = 0; j < 4; ++j)
#pragma unroll
      for (int r = 0; r < 4; ++r) acc[i][j][r] = 0.f;

  const int r_ = tid >> 2;
  const int cg = (tid & 3) ^ ((r_ >> 1) & 3);
  const u16* Ag0 = A + (size_t)(mb + r_) * K + cg * 8;
  const u16* Bg0 = B + (size_t)(nb + r_) * K + cg * 8;
  const u16* Bg1 = B + (size_t)(nb + r_ + 64) * K + cg * 8;
  const int l0 = wave * 512;
  const int l1 = 2048 + wave * 512;
  const int sw = (fm >> 1) & 3;

  int buf = 0;
  glds16(Ag0, As + l0);
  glds16(Bg0, Bs + l0);
  glds16(Bg1, Bs + l1);

  for (int k0 = 0; k0 < K; k0 += 32) {
    __syncthreads();
    if (k0 + 32 < K) {
      int aoff = (buf ^ 1) * 2048, boff = (buf ^ 1) * 4096;
      glds16(Ag0 + k0 + 32, As + aoff + l0);
      glds16(Bg0 + k0 + 32, Bs + boff + l0);
      glds16(Bg1 + k0 + 32, Bs + boff + l1);
    }
    const u16* Ab = As + buf * 2048;
    const u16* Bb = Bs + buf * 4096;
    bf16x8 av[2], bv[4];
#pragma unroll
    for (int t = 0; t < 2; ++t)
      av[t] = *(const bf16x8*)(Ab + (wm + t * 16 + fm) * 32 + ((fq ^ sw) * 8));
#pragma unroll
    for (int t = 0; t < 4; ++t)
      bv[t] = *(const bf16x8*)(Bb + (wn + t * 16 + fm) * 32 + ((fq ^ sw) * 8));
#pragma unroll
    for (int i = 0; i < 2; ++i)
#pragma unroll
      for (int j = 0; j < 4; ++j)
        acc[i][j] = __builtin_amdgcn_mfma_f32_16x16x32_bf16(av[i], bv[j], acc[i][j], 0, 0, 0);
    buf ^= 1;
  }
#pragma unroll
  for (int i = 0; i < 2; ++i)
#pragma unroll
    for (int j = 0; j < 4; ++j)
#pragma unroll
      for (int r = 0; r < 4; ++r) {
        int row = mb + wm + i * 16 + fq * 4 + r;
        int col = nb + wn + j * 16 + fm;
        C[(size_t)row * N + col] = acc[i][j][r];
      }
}

// ---------------- causal flash attention v21: V from L2, K staged ----------
// v20 (46-49 us) + two coupled changes:
// (1) V is NOT LDS-staged: per-lane global fragment loads (addressing
//     proven in v13). The v13 failure was load ORDER: pvb was issued after
//     the glds16 prefetch, so waiting on pvb forced vmcnt(0) (vmcnt retires
//     in issue order) and drained the prefetch. Here pvb loads are issued
//     FIRST (oldest), then the K glds16 — pvb completes at vmcnt(1) and the
//     prefetch stays in flight. Halves the LDS-read pipe (22 -> 11 us),
//     removes V staging writes. LDS 32,768 -> 16,384 B.
// (2) XCD head-chunk swizzle (T1): blocks mapped so XCD k = bid%8 owns
//     heads {2k, 2k+1} -> per-XCD K+V working set 2 MB, L2-resident, so the
//     V global reads are L2 hits. Bijective (1024 % 8 == 0), longest-first
//     preserved within each XCD.
template <int STORE, int NSPLIT>
__global__ __launch_bounds__(512, 4) void attn_kernel(const u16* __restrict__ Q,
                                                      const u16* __restrict__ K,
                                                      const u16* __restrict__ Vt,
                                                      void* __restrict__ Oacc,
                                                      float* __restrict__ Lacc) {
  __shared__ __align__(16) u16 Ks[2 * 4096];   // 2 x (64 key x 64 d), swizzled, rows permuted
  const int tid = threadIdx.x;
  const int w = tid >> 6, lane = tid & 63;
  const int fm = lane & 15, fq = lane >> 4;
  const int bid = blockIdx.x;
  int qt, h, half, kbase, nlocal;
  if (NSPLIT == 4) {
    // XCD swizzle: k = bid&7 owns head-pair {2k,2k+1}; within an XCD the
    // blocks run longest-first. swz = k*128 + (bid>>3); decode
    // [hp:3][qt-desc:4][chunk:2][hbit:1].
    int swz = (bid & 7) * 128 + (bid >> 3);
    int hp = swz >> 7;
    int inner = swz & 127;
    qt = 15 - (inner >> 3);
    half = (inner >> 1) & 3;
    h = hp * 2 + (inner & 1);
    nlocal = qt + 1;
    kbase = half * nlocal;
  } else {
    // bid in [0,512): complement-paired halves
    const int u = bid & 255, hi = bid >> 8;
    h = u & 15;
    const int qt0 = u >> 4;
    qt = hi ? qt0 : 15 - qt0;
    half = hi;
    nlocal = 2 * qt + 2;
    kbase = half * nlocal;
  }
  const int qb = qt * 256 + w * 32;
  const int dtile = qb >> 6;        // == dtile: partial mask; > dtile: skip

  bf16x8 q0[2], q1[2];
#pragma unroll
  for (int g = 0; g < 2; ++g) {
    const u16* qp = Q + (size_t)(qb + g * 16 + fm) * DM + h * DH + fq * 8;
    q0[g] = *(const bf16x8*)(qp);
    q1[g] = *(const bf16x8*)(qp + 32);
  }
  f32x4 o[2][4];
  f32x4 ls[2];
#pragma unroll
  for (int g = 0; g < 2; ++g) {
#pragma unroll
    for (int r = 0; r < 4; ++r) ls[g][r] = 0.f;
#pragma unroll
    for (int c4 = 0; c4 < 4; ++c4)
#pragma unroll
      for (int r = 0; r < 4; ++r) o[g][c4][r] = 0.f;
  }
  const short ONEB = (short)0x3F80;  // 1.0 bf16
  const bf16x8 vone = {ONEB, ONEB, ONEB, ONEB, ONEB, ONEB, ONEB, ONEB};

  // K staging: 512 slots x 16B = one full 64x64 tile; slot = tid.
  // row = tid>>3, stored chunk = tid&7, global chunk = (tid&7) ^ (row&7).
  // K rows permuted: LDS row s holds global key g(s), the 6-bit permutation
  // [b5 b4 b3 b2 b1 b0] -> key bits [b5 | b3 b2 | b4 | b1 b0], which makes
  // st's (t,fq,r) layout coincide with the MFMA B-operand k = fq*8+(t&1)*4+r.
  const int rr = tid >> 3;                 // [0,64)  (LDS row)
  const int cc8 = (tid & 7) ^ (rr & 7);
  const int grr = ((rr >> 5) << 5) | (((rr >> 2) & 3) << 3) | (((rr >> 4) & 1) << 2) | (rr & 3);
  const u16* Kg = K + (size_t)grr * DM + h * DH + cc8 * 8;
  const int l0 = w * 512;                  // wave-uniform LDS base (u16)
  const int sw7 = fm & 7;
  const f32x4 zf = {0.f, 0.f, 0.f, 0.f};

  // per-lane V fragment base (global; L2-hit with the head-chunk swizzle)
  const u16* Vfrag = Vt + (size_t)(h * DH + fm) * S_LEN + fq * 8;  // + c4*16*S_LEN + ktg*64

  glds16(Kg + (size_t)kbase * 64 * DM, Ks + l0);

  int buf = 0;
  for (int kl = 0; kl < nlocal; ++kl) {
    const int ktg = kbase + kl;
    __syncthreads();
    const bool active = (ktg <= dtile);
    // (1) V fragments from global — issued FIRST so they are the oldest
    // VMEM ops; their completion wait is vmcnt(1), not a full drain.
    bf16x8 pvb[4][2];
    if (active) {
#pragma unroll
      for (int c4 = 0; c4 < 4; ++c4) {
        const u16* vr = Vfrag + (size_t)(c4 * 16) * S_LEN + ktg * 64;
        pvb[c4][0] = *(const bf16x8*)(vr);
        pvb[c4][1] = *(const bf16x8*)(vr + 32);
      }
    }
    // (2) K prefetch for the next tile (youngest VMEM op; drains at the
    // next barrier, one full iteration away)
    if (kl + 1 < nlocal) {
      glds16(Kg + (size_t)(ktg + 1) * 64 * DM, Ks + (buf ^ 1) * 4096 + l0);
    }
    if (active) {
      const u16* Kb = Ks + buf * 4096;

      // S^T = K * Q^T over permuted-staged K rows: st[g][t][r] holds
      // P-logits for key = ktg*64 + (t>>1)*32 + fq*8 + (t&1)*4 + r, q = fm
      f32x4 st[2][4];
#pragma unroll
      for (int t = 0; t < 4; ++t) {
        const u16* kr = Kb + (t * 16 + fm) * 64;
        bf16x8 ka = *(const bf16x8*)(kr + ((fq ^ sw7) * 8));
        bf16x8 kb2 = *(const bf16x8*)(kr + (((fq + 4) ^ sw7) * 8));
#pragma unroll
        for (int g = 0; g < 2; ++g) {
          f32x4 s = __builtin_amdgcn_mfma_f32_16x16x32_bf16(ka, q0[g], zf, 0, 0, 0);
          st[g][t] = __builtin_amdgcn_mfma_f32_16x16x32_bf16(kb2, q1[g], s, 0, 0, 0);
        }
      }
      if (ktg == dtile) {  // diagonal tile: partial causal mask (permuted keys)
#pragma unroll
        for (int g = 0; g < 2; ++g) {
          int qg = qb + g * 16 + fm;
#pragma unroll
          for (int t = 0; t < 4; ++t) {
            int key = ktg * 64 + (t >> 1) * 32 + fq * 8 + (t & 1) * 4;
#pragma unroll
            for (int r = 0; r < 4; ++r)
              st[g][t][r] = (key + r > qg) ? -1e30f : st[g][t][r];
          }
        }
      }
      // register-only softmax+PV: exp2 -> pack -> MFMA (no LDS round-trip)
#pragma unroll
      for (int g = 0; g < 2; ++g) {
        unsigned pw[8];
#pragma unroll
        for (int t = 0; t < 4; ++t) {
          float p0 = __builtin_amdgcn_exp2f(st[g][t][0]);
          float p1 = __builtin_amdgcn_exp2f(st[g][t][1]);
          float p2 = __builtin_amdgcn_exp2f(st[g][t][2]);
          float p3 = __builtin_amdgcn_exp2f(st[g][t][3]);
          pw[t * 2] = pk2t(p0, p1);
          pw[t * 2 + 1] = pk2t(p2, p3);
        }
        uint4 u0 = {pw[0], pw[1], pw[2], pw[3]};
        uint4 u1 = {pw[4], pw[5], pw[6], pw[7]};
        bf16x8 pb0 = __builtin_bit_cast(bf16x8, u0);  // B-frag, keys 0..31 of tile
        bf16x8 pb1 = __builtin_bit_cast(bf16x8, u1);  // B-frag, keys 32..63
        ls[g] = __builtin_amdgcn_mfma_f32_16x16x32_bf16(vone, pb0, ls[g], 0, 0, 0);
        ls[g] = __builtin_amdgcn_mfma_f32_16x16x32_bf16(vone, pb1, ls[g], 0, 0, 0);
#pragma unroll
        for (int c4 = 0; c4 < 4; ++c4) {
          o[g][c4] = __builtin_amdgcn_mfma_f32_16x16x32_bf16(pvb[c4][0], pb0, o[g][c4], 0, 0, 0);
          o[g][c4] = __builtin_amdgcn_mfma_f32_16x16x32_bf16(pvb[c4][1], pb1, o[g][c4], 0, 0, 0);
        }
      }
    }
    buf ^= 1;
  }
  // D layout [d][q]: lane (fm,fq) reg r holds o for q = g*16+fm,
  // d = c4*16 + fq*4 + r. ls[g][*] all hold l[q = g*16+fm].
  if (STORE) {
    // bf16 partials: Opart[half][h][row][d] u16 (RNE), Lpart fp32
    u16* Ob = (u16*)Oacc + (((size_t)half * NH + h) * S_LEN + qt * 256 + w * 32) * DH;
    float* Lb = Lacc + ((size_t)half * NH + h) * S_LEN + qt * 256 + w * 32;
#pragma unroll
    for (int g = 0; g < 2; ++g) {
      if (fq == 0) Lb[g * 16 + fm] = ls[g][0];
#pragma unroll
      for (int c4 = 0; c4 < 4; ++c4) {
        uint2 pv;
        pv.x = pk2(o[g][c4][0], o[g][c4][1]);
        pv.y = pk2(o[g][c4][2], o[g][c4][3]);
        *(uint2*)(Ob + (size_t)(g * 16 + fm) * DH + c4 * 16 + fq * 4) = pv;
      }
    }
  } else {
    // fallback: atomic accumulate into shared fp32 Oacc/Lacc
    float* Ob = (float*)Oacc + ((size_t)h * S_LEN + qt * 256 + w * 32) * DH;
    float* Lb = Lacc + h * S_LEN + qt * 256 + w * 32;
#pragma unroll
    for (int g = 0; g < 2; ++g) {
      if (fq == 0) unsafeAtomicAdd(Lb + g * 16 + fm, ls[g][0]);
#pragma unroll
      for (int c4 = 0; c4 < 4; ++c4)
#pragma unroll
        for (int r = 0; r < 4; ++r)
          unsafeAtomicAdd(Ob + (size_t)(g * 16 + fm) * DH + c4 * 16 + fq * 4 + r, o[g][c4][r]);
    }
  }
}

// ---------------- combine (4-split, bf16 partials) --------------------------
__global__ __launch_bounds__(256) void combine4_kernel(const u16* __restrict__ O,
                                                       const float* __restrict__ L,
                                                       u16* __restrict__ Ctx) {
  int idx = blockIdx.x * 256 + threadIdx.x;  // 1,048,576 threads
  int d4 = (idx & 15) * 4;
  int hh = (idx >> 4) & 15;
  int row = idx >> 8;
  const size_t OS = (size_t)NH * S_LEN * DH, LS = (size_t)NH * S_LEN;
  size_t ob = ((size_t)hh * S_LEN + row) * DH + d4;
  size_t lb = (size_t)hh * S_LEN + row;
  float s0 = 0.f, s1 = 0.f, s2 = 0.f, s3 = 0.f;
#pragma unroll
  for (int s = 0; s < 4; ++s) {
    uint2 v = *(const uint2*)(O + s * OS + ob);
    s0 += b2f(v.x & 0xffffu);
    s1 += b2f(v.x >> 16);
    s2 += b2f(v.y & 0xffffu);
    s3 += b2f(v.y >> 16);
  }
  float il = 1.0f / (L[lb] + L[LS + lb] + L[2 * LS + lb] + L[3 * LS + lb]);
  uint2 o;
  o.x = pk2(s0 * il, s1 * il);
  o.y = pk2(s2 * il, s3 * il);
  *(uint2*)(Ctx + (size_t)row * DM + hh * DH + d4) = o;
}

// ---------------- combine (atomic fallback): Ctx = bf16(Oacc / Lacc) --------
__global__ __launch_bounds__(256) void combine_kernel(const float* __restrict__ Oacc,
                                                      const float* __restrict__ Lacc,
                                                      u16* __restrict__ Ctx) {
  int idx = blockIdx.x * 256 + threadIdx.x;  // 1,048,576 threads
  int d4 = (idx & 15) * 4;
  int hh = (idx >> 4) & 15;
  int row = idx >> 8;
  float4 a = *(const float4*)(Oacc + ((size_t)hh * S_LEN + row) * DH + d4);
  float il = 1.0f / Lacc[hh * S_LEN + row];
  uint2 o;
  o.x = pk2(a.x * il, a.y * il);
  o.y = pk2(a.z * il, a.w * il);
  *(uint2*)(Ctx + (size_t)row * DM + hh * DH + d4) = o;
}

extern "C" void kernel_launch(void* const* d_in, const int* in_sizes, int n_in,
                              void* d_out, int out_size, void* d_ws, size_t ws_size,
                              hipStream_t stream) {
  const float* x  = (const float*)d_in[0];
  const float* Wq = (const float*)d_in[1];
  const float* Wk = (const float*)d_in[2];
  const float* Wv = (const float*)d_in[3];
  const float* Wo = (const float*)d_in[4];
  float* out = (float*)d_out;

  const size_t MB = 1u << 20;
  char* ws = (char*)d_ws;

  if (ws_size >= 72 * MB) {
    // 4-split bf16-partial layout (72 MB):
    //  [0,8)   xb -> Ctx;  [8,14) wqb/wkb/wvb -> Lpart[4] fp32 (1 MB)
    //  [14,16) wob; [16,40) Qb, Kb, Vtb; [40,72) Opart [4][16][4096][64] bf16
    u16* xb    = (u16*)(ws + 0 * MB);
    u16* wqb   = (u16*)(ws + 8 * MB);
    u16* wkb   = (u16*)(ws + 10 * MB);
    u16* wvb   = (u16*)(ws + 12 * MB);
    u16* wob   = (u16*)(ws + 14 * MB);
    u16* Qb    = (u16*)(ws + 16 * MB);
    u16* Kb    = (u16*)(ws + 24 * MB);
    u16* Vtb   = (u16*)(ws + 32 * MB);
    u16* Op    = (u16*)(ws + 40 * MB);
    float* Lp  = (float*)(ws + 8 * MB);
    u16* Ctx   = (u16*)(ws + 0 * MB);

    cvt_all<<<8192, 256, 0, stream>>>(x, Wq, Wk, Wv, Wo, xb, wqb, wkb, wvb, wob);
    qkv_gemm<<<dim3(24, 32), 256, 0, stream>>>(xb, wqb, wkb, wvb, Qb, Kb, Vtb);
    attn_kernel<1, 4><<<1024, 512, 0, stream>>>(Qb, Kb, Vtb, Op, Lp);
    combine4_kernel<<<4096, 256, 0, stream>>>(Op, Lp, Ctx);
    o_gemm<<<dim3(8, 64), 256, 0, stream>>>(Ctx, wob, out, S_LEN, DM, DM);
  } else {
    // fallback: round-0 layout + atomic path
    u16* xb    = (u16*)(ws + 0 * MB);
    u16* wqb   = (u16*)(ws + 8 * MB);
    u16* wkb   = (u16*)(ws + 10 * MB);
    u16* wvb   = (u16*)(ws + 12 * MB);
    float* Oacc = (float*)(ws + 0 * MB);
    float* Lacc = (float*)(ws + 16 * MB);
    u16* wob   = (u16*)(ws + 17 * MB);
    u16* Qb    = (u16*)(ws + 19 * MB);
    u16* Kb    = (u16*)(ws + 27 * MB);
    u16* Vtb   = (u16*)(ws + 35 * MB);
    u16* Ctx   = (u16*)(ws + 43 * MB);

    cvt_all<<<8192, 256, 0, stream>>>(x, Wq, Wk, Wv, Wo, xb, wqb, wkb, wvb, wob);
    qkv_gemm<<<dim3(24, 32), 256, 0, stream>>>(xb, wqb, wkb, wvb, Qb, Kb, Vtb);
    zero_kernel<<<4160, 256, 0, stream>>>((float4*)Oacc);
    attn_kernel<0, 2><<<512, 512, 0, stream>>>(Qb, Kb, Vtb, Oacc, Lacc);
    combine_kernel<<<4096, 256, 0, stream>>>(Oacc, Lacc, Ctx);
    o_gemm<<<dim3(8, 64), 256, 0, stream>>>(Ctx, wob, out, S_LEN, DM, DM);
  }
}

// Round 17
// 188.397 us; speedup vs baseline: 1.4621x; 1.4621x over previous
//
#include <hip/hip_runtime.h>
#include <hip/hip_bf16.h>

typedef __attribute__((ext_vector_type(8))) short bf16x8;
typedef __attribute__((ext_vector_type(4))) float f32x4;
typedef unsigned short u16;

#define S_LEN 4096
#define DM 1024
#define NH 16
#define DH 64

// manual RNE fp32->bf16 (inputs never NaN here): 3 VALU ops
__device__ __forceinline__ u16 f2b_rne(float f) {
  unsigned u = __builtin_bit_cast(unsigned, f);
  return (u16)((u + 0x7fffu + ((u >> 16) & 1u)) >> 16);
}
// pack two fp32 -> bf16x2 in one u32 (RNE)
__device__ __forceinline__ unsigned pk2(float a, float b) {
  unsigned ua = __builtin_bit_cast(unsigned, a);
  unsigned ub = __builtin_bit_cast(unsigned, b);
  ua = (ua + 0x7fffu + ((ua >> 16) & 1u)) >> 16;
  ub = (ub + 0x7fffu + ((ub >> 16) & 1u)) & 0xffff0000u;
  return ua | ub;
}
// pack two fp32 -> bf16x2, TRUNCATED: single v_perm_b32 (low=a, high=b).
// bias cancels in softmax (same P in numerator and denominator).
__device__ __forceinline__ unsigned pk2t(float a, float b) {
  return __builtin_amdgcn_perm(__builtin_bit_cast(unsigned, b),
                               __builtin_bit_cast(unsigned, a), 0x07060302u);
}
// bf16 (u16) -> f32
__device__ __forceinline__ float b2f(unsigned u) {
  return __builtin_bit_cast(float, u << 16);
}

// global -> LDS direct (16B per lane; lds base must be wave-uniform)
__device__ __forceinline__ void glds16(const u16* g, u16* l) {
  __builtin_amdgcn_global_load_lds(
      (const __attribute__((address_space(1))) unsigned int*)g,
      (__attribute__((address_space(3))) unsigned int*)l, 16, 0, 0);
}

// ---------------- fp32 -> bf16, all 5 inputs in one launch ----------------
__global__ __launch_bounds__(256) void cvt_all(const float* __restrict__ x,
                                               const float* __restrict__ Wq,
                                               const float* __restrict__ Wk,
                                               const float* __restrict__ Wv,
                                               const float* __restrict__ Wo,
                                               u16* __restrict__ xb, u16* __restrict__ wqb,
                                               u16* __restrict__ wkb, u16* __restrict__ wvb,
                                               u16* __restrict__ wob) {
  int idx = (blockIdx.x * 256 + threadIdx.x) * 4;
  const float* src;
  u16* dst;
  int o;
  if (idx < 4194304) {
    src = x; dst = xb; o = idx;
  } else {
    int t = idx - 4194304;
    int wsel = t >> 20;
    o = t & 1048575;
    src = (wsel == 0) ? Wq : (wsel == 1) ? Wk : (wsel == 2) ? Wv : Wo;
    dst = (wsel == 0) ? wqb : (wsel == 1) ? wkb : (wsel == 2) ? wvb : wob;
  }
  float4 v = *(const float4*)(src + o);
  uint2 ov;
  ov.x = pk2(v.x, v.y);
  ov.y = pk2(v.z, v.w);
  *(uint2*)(dst + o) = ov;
}

// ---------------- zero the O/L accumulators (fallback path only) -----------
__global__ __launch_bounds__(256) void zero_kernel(float4* __restrict__ p) {
  p[blockIdx.x * 256 + threadIdx.x] = float4{0.f, 0.f, 0.f, 0.f};
}

// ---------------- fused QKV NT-GEMM with RoPE epilogue; V written transposed
// grid (24, 32): mat = bx>>3 (0=Q rope+scale, 1=K rope, 2=V -> Vt), nb = (bx&7)*128
__global__ __launch_bounds__(256) void qkv_gemm(const u16* __restrict__ A,
                                                const u16* __restrict__ Wq,
                                                const u16* __restrict__ Wk,
                                                const u16* __restrict__ Wv,
                                                u16* __restrict__ Qo, u16* __restrict__ Ko,
                                                u16* __restrict__ Vt) {
  __shared__ __align__(16) u16 As[2 * 128 * 32];
  __shared__ __align__(16) u16 Bs[2 * 128 * 32];
  const int mat = blockIdx.x >> 3;
  const u16* B = (mat == 0) ? Wq : (mat == 1) ? Wk : Wv;
  const int K = DM, N = DM;
  const int tid = threadIdx.x;
  const int wave = tid >> 6, lane = tid & 63;
  const int fm = lane & 15, fq = lane >> 4;
  const int mb = blockIdx.y * 128, nb = (blockIdx.x & 7) * 128;
  const int wm = (wave & 1) * 64, wn = (wave >> 1) * 64;

  f32x4 acc[4][4];
#pragma unroll
  for (int i = 0; i < 4; ++i)
#pragma unroll
    for (int j = 0; j < 4; ++j)
#pragma unroll
      for (int r = 0; r < 4; ++r) acc[i][j][r] = 0.f;

  const int r_ = tid >> 2;
  const int cg = (tid & 3) ^ ((r_ >> 1) & 3);
  const u16* Ag0 = A + (size_t)(mb + r_) * K + cg * 8;
  const u16* Ag1 = A + (size_t)(mb + r_ + 64) * K + cg * 8;
  const u16* Bg0 = B + (size_t)(nb + r_) * K + cg * 8;
  const u16* Bg1 = B + (size_t)(nb + r_ + 64) * K + cg * 8;
  const int l0 = wave * 512;
  const int l1 = 2048 + wave * 512;
  const int sw = (fm >> 1) & 3;

  int buf = 0;
  glds16(Ag0, As + l0);
  glds16(Ag1, As + l1);
  glds16(Bg0, Bs + l0);
  glds16(Bg1, Bs + l1);

  for (int k0 = 0; k0 < K; k0 += 32) {
    __syncthreads();
    if (k0 + 32 < K) {
      int bo = (buf ^ 1) * 4096;
      glds16(Ag0 + k0 + 32, As + bo + l0);
      glds16(Ag1 + k0 + 32, As + bo + l1);
      glds16(Bg0 + k0 + 32, Bs + bo + l0);
      glds16(Bg1 + k0 + 32, Bs + bo + l1);
    }
    const u16* Ab = As + buf * 4096;
    const u16* Bb = Bs + buf * 4096;
    bf16x8 av[4], bv[4];
#pragma unroll
    for (int t = 0; t < 4; ++t) {
      av[t] = *(const bf16x8*)(Ab + (wm + t * 16 + fm) * 32 + ((fq ^ sw) * 8));
      bv[t] = *(const bf16x8*)(Bb + (wn + t * 16 + fm) * 32 + ((fq ^ sw) * 8));
    }
#pragma unroll
    for (int i = 0; i < 4; ++i)
#pragma unroll
      for (int j = 0; j < 4; ++j)
        acc[i][j] = __builtin_amdgcn_mfma_f32_16x16x32_bf16(av[i], bv[j], acc[i][j], 0, 0, 0);
    buf ^= 1;
  }

  if (mat < 2) {
    // RoPE epilogue (in-register): pairs (d, d+32) = regs (j, j+2), d = j*16+fm, j in {0,1}
    u16* Out = (mat == 0) ? Qo : Ko;
    const float qs = (mat == 0) ? 0.1803368801111204f : 1.0f;  // 0.125*log2(e) for Q
    const float c1 = -9.2103403719761836f / 32.f;              // -ln(10000)/32
    const float if0 = __expf((float)fm * c1);
    const float if1 = __expf((float)(16 + fm) * c1);
#pragma unroll
    for (int ii = 0; ii < 4; ++ii) {
#pragma unroll
      for (int r = 0; r < 4; ++r) {
        float s = (float)(mb + wm + ii * 16 + fq * 4 + r);
#pragma unroll
        for (int jp = 0; jp < 2; ++jp) {
          float ang = s * (jp ? if1 : if0);
          float sn, cs;
          __sincosf(ang, &sn, &cs);
          float a = acc[ii][jp][r], b = acc[ii][jp + 2][r];
          acc[ii][jp][r] = (a * cs - b * sn) * qs;
          acc[ii][jp + 2][r] = (b * cs + a * sn) * qs;
        }
      }
    }
#pragma unroll
    for (int i = 0; i < 4; ++i)
#pragma unroll
      for (int j = 0; j < 4; ++j)
#pragma unroll
        for (int r = 0; r < 4; ++r) {
          int row = mb + wm + i * 16 + fq * 4 + r;
          int col = nb + wn + j * 16 + fm;
          Out[(size_t)row * N + col] = f2b_rne(acc[i][j][r]);
        }
  } else {
    // V: write transposed Vt[col][row]; 4 r-values are contiguous rows -> 8B store
#pragma unroll
    for (int i = 0; i < 4; ++i)
#pragma unroll
      for (int j = 0; j < 4; ++j) {
        int col = nb + wn + j * 16 + fm;
        int row0 = mb + wm + i * 16 + fq * 4;
        uint2 pv;
        pv.x = pk2(acc[i][j][0], acc[i][j][1]);
        pv.y = pk2(acc[i][j][2], acc[i][j][3]);
        *(uint2*)(Vt + (size_t)col * S_LEN + row0) = pv;
      }
  }
}

// ---------------- O-projection NT GEMM, 64x128 tiles (fp32 out) -------------
// grid (8, 64): nb = bx*128, mb = by*64. 512 blocks -> real occupancy (vs 256).
__global__ __launch_bounds__(256) void o_gemm(const u16* __restrict__ A,
                                              const u16* __restrict__ B,
                                              float* __restrict__ C, int M, int N, int K) {
  __shared__ __align__(16) u16 As[2 * 64 * 32];
  __shared__ __align__(16) u16 Bs[2 * 128 * 32];
  const int tid = threadIdx.x;
  const int wave = tid >> 6, lane = tid & 63;
  const int fm = lane & 15, fq = lane >> 4;
  const int mb = blockIdx.y * 64, nb = blockIdx.x * 128;
  const int wm = (wave & 1) * 32, wn = (wave >> 1) * 64;

  f32x4 acc[2][4];
#pragma unroll
  for (int i = 0; i < 2; ++i)
#pragma unroll
    for (int j = 0; j < 4; ++j)
#pragma unroll
      for (int r = 0; r < 4; ++r) acc[i][j][r] = 0.f;

  const int r_ = tid >> 2;
  const int cg = (tid & 3) ^ ((r_ >> 1) & 3);
  const u16* Ag0 = A + (size_t)(mb + r_) * K + cg * 8;
  const u16* Bg0 = B + (size_t)(nb + r_) * K + cg * 8;
  const u16* Bg1 = B + (size_t)(nb + r_ + 64) * K + cg * 8;
  const int l0 = wave * 512;
  const int l1 = 2048 + wave * 512;
  const int sw = (fm >> 1) & 3;

  int buf = 0;
  glds16(Ag0, As + l0);
  glds16(Bg0, Bs + l0);
  glds16(Bg1, Bs + l1);

  for (int k0 = 0; k0 < K; k0 += 32) {
    __syncthreads();
    if (k0 + 32 < K) {
      int aoff = (buf ^ 1) * 2048, boff = (buf ^ 1) * 4096;
      glds16(Ag0 + k0 + 32, As + aoff + l0);
      glds16(Bg0 + k0 + 32, Bs + boff + l0);
      glds16(Bg1 + k0 + 32, Bs + boff + l1);
    }
    const u16* Ab = As + buf * 2048;
    const u16* Bb = Bs + buf * 4096;
    bf16x8 av[2], bv[4];
#pragma unroll
    for (int t = 0; t < 2; ++t)
      av[t] = *(const bf16x8*)(Ab + (wm + t * 16 + fm) * 32 + ((fq ^ sw) * 8));
#pragma unroll
    for (int t = 0; t < 4; ++t)
      bv[t] = *(const bf16x8*)(Bb + (wn + t * 16 + fm) * 32 + ((fq ^ sw) * 8));
#pragma unroll
    for (int i = 0; i < 2; ++i)
#pragma unroll
      for (int j = 0; j < 4; ++j)
        acc[i][j] = __builtin_amdgcn_mfma_f32_16x16x32_bf16(av[i], bv[j], acc[i][j], 0, 0, 0);
    buf ^= 1;
  }
#pragma unroll
  for (int i = 0; i < 2; ++i)
#pragma unroll
    for (int j = 0; j < 4; ++j)
#pragma unroll
      for (int r = 0; r < 4; ++r) {
        int row = mb + wm + i * 16 + fq * 4 + r;
        int col = nb + wn + j * 16 + fm;
        C[(size_t)row * N + col] = acc[i][j][r];
      }
}

// ---------------- causal flash attention v20: v17 + bf16 partials ----------
// Best-measured configuration (round 14: 190.5 us total, attn 46-49 us).
// Reg-only softmax via permuted K staging (0 bank conflicts), 512 threads,
// 8 waves x 32 q-rows, NSPLIT=4 chunks of qt+1 tiles, grid 1024
// longest-first, bf16 O-partials. v21's V-from-L2 (134 us, L2 thrash:
// WRITE 123 MB) is REVERTED — V staging in LDS is load-bearing.
template <int STORE, int NSPLIT>
__global__ __launch_bounds__(512, 4) void attn_kernel(const u16* __restrict__ Q,
                                                      const u16* __restrict__ K,
                                                      const u16* __restrict__ Vt,
                                                      void* __restrict__ Oacc,
                                                      float* __restrict__ Lacc) {
  __shared__ __align__(16) u16 Ks[2 * 4096];   // 2 x (64 key x 64 d), swizzled, rows permuted
  __shared__ __align__(16) u16 Vs[2 * 4096];   // 2 x (64 d x 64 key), swizzled
  const int tid = threadIdx.x;
  const int w = tid >> 6, lane = tid & 63;
  const int fm = lane & 15, fq = lane >> 4;
  const int bid = blockIdx.x;
  int qt, h, half, kbase, nlocal;
  if (NSPLIT == 4) {
    // bid in [0,1024): [qt-desc:4][chunk:2][h:4]; chunks of qt+1 tiles each
    qt = 15 - (bid >> 6);
    half = (bid >> 4) & 3;
    h = bid & 15;
    nlocal = qt + 1;
    kbase = half * nlocal;
  } else {
    // bid in [0,512): complement-paired halves
    const int u = bid & 255, hi = bid >> 8;
    h = u & 15;
    const int qt0 = u >> 4;
    qt = hi ? qt0 : 15 - qt0;
    half = hi;
    nlocal = 2 * qt + 2;
    kbase = half * nlocal;
  }
  const int qb = qt * 256 + w * 32;
  const int dtile = qb >> 6;        // == dtile: partial mask; > dtile: skip

  bf16x8 q0[2], q1[2];
#pragma unroll
  for (int g = 0; g < 2; ++g) {
    const u16* qp = Q + (size_t)(qb + g * 16 + fm) * DM + h * DH + fq * 8;
    q0[g] = *(const bf16x8*)(qp);
    q1[g] = *(const bf16x8*)(qp + 32);
  }
  f32x4 o[2][4];
  f32x4 ls[2];
#pragma unroll
  for (int g = 0; g < 2; ++g) {
#pragma unroll
    for (int r = 0; r < 4; ++r) ls[g][r] = 0.f;
#pragma unroll
    for (int c4 = 0; c4 < 4; ++c4)
#pragma unroll
      for (int r = 0; r < 4; ++r) o[g][c4][r] = 0.f;
  }
  const short ONEB = (short)0x3F80;  // 1.0 bf16
  const bf16x8 vone = {ONEB, ONEB, ONEB, ONEB, ONEB, ONEB, ONEB, ONEB};

  // staging: 512 slots x 16B = one full 64x64 tile; slot = tid.
  // row = tid>>3, stored chunk = tid&7, global chunk = (tid&7) ^ (row&7).
  // K rows permuted: LDS row s holds global key g(s), the 6-bit permutation
  // [b5 b4 b3 b2 b1 b0] -> key bits [b5 | b3 b2 | b4 | b1 b0], which makes
  // st's (t,fq,r) layout coincide with the MFMA B-operand k = fq*8+(t&1)*4+r.
  const int rr = tid >> 3;                 // [0,64)  (LDS row)
  const int cc8 = (tid & 7) ^ (rr & 7);
  const int grr = ((rr >> 5) << 5) | (((rr >> 2) & 3) << 3) | (((rr >> 4) & 1) << 2) | (rr & 3);
  const u16* Kg = K + (size_t)grr * DM + h * DH + cc8 * 8;
  const u16* Vg = Vt + (size_t)(h * DH + rr) * S_LEN + cc8 * 8;
  const int l0 = w * 512;                  // wave-uniform LDS base (u16)
  const int sw7 = fm & 7;
  const f32x4 zf = {0.f, 0.f, 0.f, 0.f};

  glds16(Kg + (size_t)kbase * 64 * DM, Ks + l0);
  glds16(Vg + kbase * 64, Vs + l0);

  int buf = 0;
  for (int kl = 0; kl < nlocal; ++kl) {
    const int ktg = kbase + kl;
    __syncthreads();
    if (kl + 1 < nlocal) {
      int bo = (buf ^ 1) * 4096;
      glds16(Kg + (size_t)(ktg + 1) * 64 * DM, Ks + bo + l0);
      glds16(Vg + (ktg + 1) * 64, Vs + bo + l0);
    }
    if (ktg <= dtile) {
      const u16* Kb = Ks + buf * 4096;
      const u16* Vb = Vs + buf * 4096;

      // S^T = K * Q^T over permuted-staged K rows: st[g][t][r] holds
      // P-logits for key = ktg*64 + (t>>1)*32 + fq*8 + (t&1)*4 + r, q = fm
      f32x4 st[2][4];
#pragma unroll
      for (int t = 0; t < 4; ++t) {
        const u16* kr = Kb + (t * 16 + fm) * 64;
        bf16x8 ka = *(const bf16x8*)(kr + ((fq ^ sw7) * 8));
        bf16x8 kb2 = *(const bf16x8*)(kr + (((fq + 4) ^ sw7) * 8));
#pragma unroll
        for (int g = 0; g < 2; ++g) {
          f32x4 s = __builtin_amdgcn_mfma_f32_16x16x32_bf16(ka, q0[g], zf, 0, 0, 0);
          st[g][t] = __builtin_amdgcn_mfma_f32_16x16x32_bf16(kb2, q1[g], s, 0, 0, 0);
        }
      }
      if (ktg == dtile) {  // diagonal tile: partial causal mask (permuted keys)
#pragma unroll
        for (int g = 0; g < 2; ++g) {
          int qg = qb + g * 16 + fm;
#pragma unroll
          for (int t = 0; t < 4; ++t) {
            int key = ktg * 64 + (t >> 1) * 32 + fq * 8 + (t & 1) * 4;
#pragma unroll
            for (int r = 0; r < 4; ++r)
              st[g][t][r] = (key + r > qg) ? -1e30f : st[g][t][r];
          }
        }
      }
      // V A-operand fragments (unchanged addressing; shared across g)
      bf16x8 pvb[4][2];
#pragma unroll
      for (int c4 = 0; c4 < 4; ++c4) {
        const u16* vr = Vb + (c4 * 16 + fm) * 64;
        pvb[c4][0] = *(const bf16x8*)(vr + ((fq ^ sw7) * 8));
        pvb[c4][1] = *(const bf16x8*)(vr + (((fq + 4) ^ sw7) * 8));
      }
      // register-only softmax+PV: exp2 -> pack -> MFMA (no LDS, no drains)
#pragma unroll
      for (int g = 0; g < 2; ++g) {
        unsigned pw[8];
#pragma unroll
        for (int t = 0; t < 4; ++t) {
          float p0 = __builtin_amdgcn_exp2f(st[g][t][0]);
          float p1 = __builtin_amdgcn_exp2f(st[g][t][1]);
          float p2 = __builtin_amdgcn_exp2f(st[g][t][2]);
          float p3 = __builtin_amdgcn_exp2f(st[g][t][3]);
          pw[t * 2] = pk2t(p0, p1);
          pw[t * 2 + 1] = pk2t(p2, p3);
        }
        uint4 u0 = {pw[0], pw[1], pw[2], pw[3]};
        uint4 u1 = {pw[4], pw[5], pw[6], pw[7]};
        bf16x8 pb0 = __builtin_bit_cast(bf16x8, u0);  // B-frag, keys 0..31 of tile
        bf16x8 pb1 = __builtin_bit_cast(bf16x8, u1);  // B-frag, keys 32..63
        ls[g] = __builtin_amdgcn_mfma_f32_16x16x32_bf16(vone, pb0, ls[g], 0, 0, 0);
        ls[g] = __builtin_amdgcn_mfma_f32_16x16x32_bf16(vone, pb1, ls[g], 0, 0, 0);
#pragma unroll
        for (int c4 = 0; c4 < 4; ++c4) {
          o[g][c4] = __builtin_amdgcn_mfma_f32_16x16x32_bf16(pvb[c4][0], pb0, o[g][c4], 0, 0, 0);
          o[g][c4] = __builtin_amdgcn_mfma_f32_16x16x32_bf16(pvb[c4][1], pb1, o[g][c4], 0, 0, 0);
        }
      }
    }
    buf ^= 1;
  }
  // D layout [d][q]: lane (fm,fq) reg r holds o for q = g*16+fm,
  // d = c4*16 + fq*4 + r. ls[g][*] all hold l[q = g*16+fm].
  if (STORE) {
    // bf16 partials: Opart[half][h][row][d] u16 (RNE), Lpart fp32
    u16* Ob = (u16*)Oacc + (((size_t)half * NH + h) * S_LEN + qt * 256 + w * 32) * DH;
    float* Lb = Lacc + ((size_t)half * NH + h) * S_LEN + qt * 256 + w * 32;
#pragma unroll
    for (int g = 0; g < 2; ++g) {
      if (fq == 0) Lb[g * 16 + fm] = ls[g][0];
#pragma unroll
      for (int c4 = 0; c4 < 4; ++c4) {
        uint2 pv;
        pv.x = pk2(o[g][c4][0], o[g][c4][1]);
        pv.y = pk2(o[g][c4][2], o[g][c4][3]);
        *(uint2*)(Ob + (size_t)(g * 16 + fm) * DH + c4 * 16 + fq * 4) = pv;
      }
    }
  } else {
    // fallback: atomic accumulate into shared fp32 Oacc/Lacc
    float* Ob = (float*)Oacc + ((size_t)h * S_LEN + qt * 256 + w * 32) * DH;
    float* Lb = Lacc + h * S_LEN + qt * 256 + w * 32;
#pragma unroll
    for (int g = 0; g < 2; ++g) {
      if (fq == 0) unsafeAtomicAdd(Lb + g * 16 + fm, ls[g][0]);
#pragma unroll
      for (int c4 = 0; c4 < 4; ++c4)
#pragma unroll
        for (int r = 0; r < 4; ++r)
          unsafeAtomicAdd(Ob + (size_t)(g * 16 + fm) * DH + c4 * 16 + fq * 4 + r, o[g][c4][r]);
    }
  }
}

// ---------------- combine (4-split, bf16 partials) --------------------------
__global__ __launch_bounds__(256) void combine4_kernel(const u16* __restrict__ O,
                                                       const float* __restrict__ L,
                                                       u16* __restrict__ Ctx) {
  int idx = blockIdx.x * 256 + threadIdx.x;  // 1,048,576 threads
  int d4 = (idx & 15) * 4;
  int hh = (idx >> 4) & 15;
  int row = idx >> 8;
  const size_t OS = (size_t)NH * S_LEN * DH, LS = (size_t)NH * S_LEN;
  size_t ob = ((size_t)hh * S_LEN + row) * DH + d4;
  size_t lb = (size_t)hh * S_LEN + row;
  float s0 = 0.f, s1 = 0.f, s2 = 0.f, s3 = 0.f;
#pragma unroll
  for (int s = 0; s < 4; ++s) {
    uint2 v = *(const uint2*)(O + s * OS + ob);
    s0 += b2f(v.x & 0xffffu);
    s1 += b2f(v.x >> 16);
    s2 += b2f(v.y & 0xffffu);
    s3 += b2f(v.y >> 16);
  }
  float il = 1.0f / (L[lb] + L[LS + lb] + L[2 * LS + lb] + L[3 * LS + lb]);
  uint2 o;
  o.x = pk2(s0 * il, s1 * il);
  o.y = pk2(s2 * il, s3 * il);
  *(uint2*)(Ctx + (size_t)row * DM + hh * DH + d4) = o;
}

// ---------------- combine (atomic fallback): Ctx = bf16(Oacc / Lacc) --------
__global__ __launch_bounds__(256) void combine_kernel(const float* __restrict__ Oacc,
                                                      const float* __restrict__ Lacc,
                                                      u16* __restrict__ Ctx) {
  int idx = blockIdx.x * 256 + threadIdx.x;  // 1,048,576 threads
  int d4 = (idx & 15) * 4;
  int hh = (idx >> 4) & 15;
  int row = idx >> 8;
  float4 a = *(const float4*)(Oacc + ((size_t)hh * S_LEN + row) * DH + d4);
  float il = 1.0f / Lacc[hh * S_LEN + row];
  uint2 o;
  o.x = pk2(a.x * il, a.y * il);
  o.y = pk2(a.z * il, a.w * il);
  *(uint2*)(Ctx + (size_t)row * DM + hh * DH + d4) = o;
}

extern "C" void kernel_launch(void* const* d_in, const int* in_sizes, int n_in,
                              void* d_out, int out_size, void* d_ws, size_t ws_size,
                              hipStream_t stream) {
  const float* x  = (const float*)d_in[0];
  const float* Wq = (const float*)d_in[1];
  const float* Wk = (const float*)d_in[2];
  const float* Wv = (const float*)d_in[3];
  const float* Wo = (const float*)d_in[4];
  float* out = (float*)d_out;

  const size_t MB = 1u << 20;
  char* ws = (char*)d_ws;

  if (ws_size >= 72 * MB) {
    // 4-split bf16-partial layout (72 MB):
    //  [0,8)   xb -> Ctx;  [8,14) wqb/wkb/wvb -> Lpart[4] fp32 (1 MB)
    //  [14,16) wob; [16,40) Qb, Kb, Vtb; [40,72) Opart [4][16][4096][64] bf16
    u16* xb    = (u16*)(ws + 0 * MB);
    u16* wqb   = (u16*)(ws + 8 * MB);
    u16* wkb   = (u16*)(ws + 10 * MB);
    u16* wvb   = (u16*)(ws + 12 * MB);
    u16* wob   = (u16*)(ws + 14 * MB);
    u16* Qb    = (u16*)(ws + 16 * MB);
    u16* Kb    = (u16*)(ws + 24 * MB);
    u16* Vtb   = (u16*)(ws + 32 * MB);
    u16* Op    = (u16*)(ws + 40 * MB);
    float* Lp  = (float*)(ws + 8 * MB);
    u16* Ctx   = (u16*)(ws + 0 * MB);

    cvt_all<<<8192, 256, 0, stream>>>(x, Wq, Wk, Wv, Wo, xb, wqb, wkb, wvb, wob);
    qkv_gemm<<<dim3(24, 32), 256, 0, stream>>>(xb, wqb, wkb, wvb, Qb, Kb, Vtb);
    attn_kernel<1, 4><<<1024, 512, 0, stream>>>(Qb, Kb, Vtb, Op, Lp);
    combine4_kernel<<<4096, 256, 0, stream>>>(Op, Lp, Ctx);
    o_gemm<<<dim3(8, 64), 256, 0, stream>>>(Ctx, wob, out, S_LEN, DM, DM);
  } else {
    // fallback: round-0 layout + atomic path
    u16* xb    = (u16*)(ws + 0 * MB);
    u16* wqb   = (u16*)(ws + 8 * MB);
    u16* wkb   = (u16*)(ws + 10 * MB);
    u16* wvb   = (u16*)(ws + 12 * MB);
    float* Oacc = (float*)(ws + 0 * MB);
    float* Lacc = (float*)(ws + 16 * MB);
    u16* wob   = (u16*)(ws + 17 * MB);
    u16* Qb    = (u16*)(ws + 19 * MB);
    u16* Kb    = (u16*)(ws + 27 * MB);
    u16* Vtb   = (u16*)(ws + 35 * MB);
    u16* Ctx   = (u16*)(ws + 43 * MB);

    cvt_all<<<8192, 256, 0, stream>>>(x, Wq, Wk, Wv, Wo, xb, wqb, wkb, wvb, wob);
    qkv_gemm<<<dim3(24, 32), 256, 0, stream>>>(xb, wqb, wkb, wvb, Qb, Kb, Vtb);
    zero_kernel<<<4160, 256, 0, stream>>>((float4*)Oacc);
    attn_kernel<0, 2><<<512, 512, 0, stream>>>(Qb, Kb, Vtb, Oacc, Lacc);
    combine_kernel<<<4096, 256, 0, stream>>>(Oacc, Lacc, Ctx);
    o_gemm<<<dim3(8, 64), 256, 0, stream>>>(Ctx, wob, out, S_LEN, DM, DM);
  }
}

// Round 18
// 187.249 us; speedup vs baseline: 1.4711x; 1.0061x over previous
//
#include <hip/hip_runtime.h>
#include <hip/hip_bf16.h>

typedef __attribute__((ext_vector_type(8))) short bf16x8;
typedef __attribute__((ext_vector_type(4))) float f32x4;
typedef unsigned short u16;

#define S_LEN 4096
#define DM 1024
#define NH 16
#define DH 64

// manual RNE fp32->bf16 (inputs never NaN here): 3 VALU ops
__device__ __forceinline__ u16 f2b_rne(float f) {
  unsigned u = __builtin_bit_cast(unsigned, f);
  return (u16)((u + 0x7fffu + ((u >> 16) & 1u)) >> 16);
}
// pack two fp32 -> bf16x2 in one u32 (RNE)
__device__ __forceinline__ unsigned pk2(float a, float b) {
  unsigned ua = __builtin_bit_cast(unsigned, a);
  unsigned ub = __builtin_bit_cast(unsigned, b);
  ua = (ua + 0x7fffu + ((ua >> 16) & 1u)) >> 16;
  ub = (ub + 0x7fffu + ((ub >> 16) & 1u)) & 0xffff0000u;
  return ua | ub;
}
// pack two fp32 -> bf16x2, TRUNCATED: single v_perm_b32 (low=a, high=b).
// bias cancels in softmax (same P in numerator and denominator).
__device__ __forceinline__ unsigned pk2t(float a, float b) {
  return __builtin_amdgcn_perm(__builtin_bit_cast(unsigned, b),
                               __builtin_bit_cast(unsigned, a), 0x07060302u);
}
// bf16 (u16) -> f32
__device__ __forceinline__ float b2f(unsigned u) {
  return __builtin_bit_cast(float, u << 16);
}

// global -> LDS direct (16B per lane; lds base must be wave-uniform)
__device__ __forceinline__ void glds16(const u16* g, u16* l) {
  __builtin_amdgcn_global_load_lds(
      (const __attribute__((address_space(1))) unsigned int*)g,
      (__attribute__((address_space(3))) unsigned int*)l, 16, 0, 0);
}

// ---------------- fp32 -> bf16, all 5 inputs in one launch ----------------
__global__ __launch_bounds__(256) void cvt_all(const float* __restrict__ x,
                                               const float* __restrict__ Wq,
                                               const float* __restrict__ Wk,
                                               const float* __restrict__ Wv,
                                               const float* __restrict__ Wo,
                                               u16* __restrict__ xb, u16* __restrict__ wqb,
                                               u16* __restrict__ wkb, u16* __restrict__ wvb,
                                               u16* __restrict__ wob) {
  int idx = (blockIdx.x * 256 + threadIdx.x) * 4;
  const float* src;
  u16* dst;
  int o;
  if (idx < 4194304) {
    src = x; dst = xb; o = idx;
  } else {
    int t = idx - 4194304;
    int wsel = t >> 20;
    o = t & 1048575;
    src = (wsel == 0) ? Wq : (wsel == 1) ? Wk : (wsel == 2) ? Wv : Wo;
    dst = (wsel == 0) ? wqb : (wsel == 1) ? wkb : (wsel == 2) ? wvb : wob;
  }
  float4 v = *(const float4*)(src + o);
  uint2 ov;
  ov.x = pk2(v.x, v.y);
  ov.y = pk2(v.z, v.w);
  *(uint2*)(dst + o) = ov;
}

// ---------------- zero the O/L accumulators (fallback path only) -----------
__global__ __launch_bounds__(256) void zero_kernel(float4* __restrict__ p) {
  p[blockIdx.x * 256 + threadIdx.x] = float4{0.f, 0.f, 0.f, 0.f};
}

// ---------------- fused QKV NT-GEMM with RoPE epilogue; V written transposed
// v2: 512 threads, 8 waves (4 row-groups x 2 col-groups), same 128x128 tile.
// Old 256-thread version capped at 12 waves/CU (grid 768 = 3 blocks/CU,
// occupancy 28%, MfmaUtil 17.8, latency-bound). 8-wave blocks lift the
// ceiling to 24 waves/CU. Per-wave acc[2][4]; wn stays a multiple of 64 so
// the in-register RoPE pairing (d, d+32) is unchanged.
// grid (24, 32): mat = bx>>3 (0=Q rope+scale, 1=K rope, 2=V -> Vt), nb = (bx&7)*128
__global__ __launch_bounds__(512) void qkv_gemm(const u16* __restrict__ A,
                                                const u16* __restrict__ Wq,
                                                const u16* __restrict__ Wk,
                                                const u16* __restrict__ Wv,
                                                u16* __restrict__ Qo, u16* __restrict__ Ko,
                                                u16* __restrict__ Vt) {
  __shared__ __align__(16) u16 As[2 * 128 * 32];
  __shared__ __align__(16) u16 Bs[2 * 128 * 32];
  const int mat = blockIdx.x >> 3;
  const u16* B = (mat == 0) ? Wq : (mat == 1) ? Wk : Wv;
  const int K = DM, N = DM;
  const int tid = threadIdx.x;
  const int wave = tid >> 6, lane = tid & 63;
  const int fm = lane & 15, fq = lane >> 4;
  const int mb = blockIdx.y * 128, nb = (blockIdx.x & 7) * 128;
  const int wm = (wave & 3) * 32, wn = (wave >> 2) * 64;

  f32x4 acc[2][4];
#pragma unroll
  for (int i = 0; i < 2; ++i)
#pragma unroll
    for (int j = 0; j < 4; ++j)
#pragma unroll
      for (int r = 0; r < 4; ++r) acc[i][j][r] = 0.f;

  // staging: 512 threads x 16B = one full 128x32 tile per array.
  // row = tid>>2 in [0,128); stored chunk = tid&3; global chunk swizzled.
  const int r_ = tid >> 2;
  const int cg = (tid & 3) ^ ((r_ >> 1) & 3);
  const u16* Ag0 = A + (size_t)(mb + r_) * K + cg * 8;
  const u16* Bg0 = B + (size_t)(nb + r_) * K + cg * 8;
  const int l0 = wave * 512;   // 8 waves x 512 u16 = 4096 u16 tile
  const int sw = (fm >> 1) & 3;

  int buf = 0;
  glds16(Ag0, As + l0);
  glds16(Bg0, Bs + l0);

  for (int k0 = 0; k0 < K; k0 += 32) {
    __syncthreads();
    if (k0 + 32 < K) {
      int bo = (buf ^ 1) * 4096;
      glds16(Ag0 + k0 + 32, As + bo + l0);
      glds16(Bg0 + k0 + 32, Bs + bo + l0);
    }
    const u16* Ab = As + buf * 4096;
    const u16* Bb = Bs + buf * 4096;
    bf16x8 av[2], bv[4];
#pragma unroll
    for (int t = 0; t < 2; ++t)
      av[t] = *(const bf16x8*)(Ab + (wm + t * 16 + fm) * 32 + ((fq ^ sw) * 8));
#pragma unroll
    for (int t = 0; t < 4; ++t)
      bv[t] = *(const bf16x8*)(Bb + (wn + t * 16 + fm) * 32 + ((fq ^ sw) * 8));
#pragma unroll
    for (int i = 0; i < 2; ++i)
#pragma unroll
      for (int j = 0; j < 4; ++j)
        acc[i][j] = __builtin_amdgcn_mfma_f32_16x16x32_bf16(av[i], bv[j], acc[i][j], 0, 0, 0);
    buf ^= 1;
  }

  if (mat < 2) {
    // RoPE epilogue (in-register): pairs (d, d+32) = regs (j, j+2), d = j*16+fm, j in {0,1}
    u16* Out = (mat == 0) ? Qo : Ko;
    const float qs = (mat == 0) ? 0.1803368801111204f : 1.0f;  // 0.125*log2(e) for Q
    const float c1 = -9.2103403719761836f / 32.f;              // -ln(10000)/32
    const float if0 = __expf((float)fm * c1);
    const float if1 = __expf((float)(16 + fm) * c1);
#pragma unroll
    for (int ii = 0; ii < 2; ++ii) {
#pragma unroll
      for (int r = 0; r < 4; ++r) {
        float s = (float)(mb + wm + ii * 16 + fq * 4 + r);
#pragma unroll
        for (int jp = 0; jp < 2; ++jp) {
          float ang = s * (jp ? if1 : if0);
          float sn, cs;
          __sincosf(ang, &sn, &cs);
          float a = acc[ii][jp][r], b = acc[ii][jp + 2][r];
          acc[ii][jp][r] = (a * cs - b * sn) * qs;
          acc[ii][jp + 2][r] = (b * cs + a * sn) * qs;
        }
      }
    }
#pragma unroll
    for (int i = 0; i < 2; ++i)
#pragma unroll
      for (int j = 0; j < 4; ++j)
#pragma unroll
        for (int r = 0; r < 4; ++r) {
          int row = mb + wm + i * 16 + fq * 4 + r;
          int col = nb + wn + j * 16 + fm;
          Out[(size_t)row * N + col] = f2b_rne(acc[i][j][r]);
        }
  } else {
    // V: write transposed Vt[col][row]; 4 r-values are contiguous rows -> 8B store
#pragma unroll
    for (int i = 0; i < 2; ++i)
#pragma unroll
      for (int j = 0; j < 4; ++j) {
        int col = nb + wn + j * 16 + fm;
        int row0 = mb + wm + i * 16 + fq * 4;
        uint2 pv;
        pv.x = pk2(acc[i][j][0], acc[i][j][1]);
        pv.y = pk2(acc[i][j][2], acc[i][j][3]);
        *(uint2*)(Vt + (size_t)col * S_LEN + row0) = pv;
      }
  }
}

// ---------------- O-projection NT GEMM, 64x128 tiles (fp32 out) -------------
// grid (8, 64): nb = bx*128, mb = by*64. 512 blocks -> real occupancy (vs 256).
__global__ __launch_bounds__(256) void o_gemm(const u16* __restrict__ A,
                                              const u16* __restrict__ B,
                                              float* __restrict__ C, int M, int N, int K) {
  __shared__ __align__(16) u16 As[2 * 64 * 32];
  __shared__ __align__(16) u16 Bs[2 * 128 * 32];
  const int tid = threadIdx.x;
  const int wave = tid >> 6, lane = tid & 63;
  const int fm = lane & 15, fq = lane >> 4;
  const int mb = blockIdx.y * 64, nb = blockIdx.x * 128;
  const int wm = (wave & 1) * 32, wn = (wave >> 1) * 64;

  f32x4 acc[2][4];
#pragma unroll
  for (int i = 0; i < 2; ++i)
#pragma unroll
    for (int j = 0; j < 4; ++j)
#pragma unroll
      for (int r = 0; r < 4; ++r) acc[i][j][r] = 0.f;

  const int r_ = tid >> 2;
  const int cg = (tid & 3) ^ ((r_ >> 1) & 3);
  const u16* Ag0 = A + (size_t)(mb + r_) * K + cg * 8;
  const u16* Bg0 = B + (size_t)(nb + r_) * K + cg * 8;
  const u16* Bg1 = B + (size_t)(nb + r_ + 64) * K + cg * 8;
  const int l0 = wave * 512;
  const int l1 = 2048 + wave * 512;
  const int sw = (fm >> 1) & 3;

  int buf = 0;
  glds16(Ag0, As + l0);
  glds16(Bg0, Bs + l0);
  glds16(Bg1, Bs + l1);

  for (int k0 = 0; k0 < K; k0 += 32) {
    __syncthreads();
    if (k0 + 32 < K) {
      int aoff = (buf ^ 1) * 2048, boff = (buf ^ 1) * 4096;
      glds16(Ag0 + k0 + 32, As + aoff + l0);
      glds16(Bg0 + k0 + 32, Bs + boff + l0);
      glds16(Bg1 + k0 + 32, Bs + boff + l1);
    }
    const u16* Ab = As + buf * 2048;
    const u16* Bb = Bs + buf * 4096;
    bf16x8 av[2], bv[4];
#pragma unroll
    for (int t = 0; t < 2; ++t)
      av[t] = *(const bf16x8*)(Ab + (wm + t * 16 + fm) * 32 + ((fq ^ sw) * 8));
#pragma unroll
    for (int t = 0; t < 4; ++t)
      bv[t] = *(const bf16x8*)(Bb + (wn + t * 16 + fm) * 32 + ((fq ^ sw) * 8));
#pragma unroll
    for (int i = 0; i < 2; ++i)
#pragma unroll
      for (int j = 0; j < 4; ++j)
        acc[i][j] = __builtin_amdgcn_mfma_f32_16x16x32_bf16(av[i], bv[j], acc[i][j], 0, 0, 0);
    buf ^= 1;
  }
#pragma unroll
  for (int i = 0; i < 2; ++i)
#pragma unroll
    for (int j = 0; j < 4; ++j)
#pragma unroll
      for (int r = 0; r < 4; ++r) {
        int row = mb + wm + i * 16 + fq * 4 + r;
        int col = nb + wn + j * 16 + fm;
        C[(size_t)row * N + col] = acc[i][j][r];
      }
}

// ---------------- causal flash attention v20: v17 + bf16 partials ----------
// Best-measured configuration (round 14/17: 188.4 us total, attn 46-49 us).
// Reg-only softmax via permuted K staging (0 bank conflicts), 512 threads,
// 8 waves x 32 q-rows, NSPLIT=4 chunks of qt+1 tiles, grid 1024
// longest-first, bf16 O-partials. V staging in LDS is load-bearing
// (V-from-L2 refuted twice: v12/v13 latency, v21 L2 thrash).
template <int STORE, int NSPLIT>
__global__ __launch_bounds__(512, 4) void attn_kernel(const u16* __restrict__ Q,
                                                      const u16* __restrict__ K,
                                                      const u16* __restrict__ Vt,
                                                      void* __restrict__ Oacc,
                                                      float* __restrict__ Lacc) {
  __shared__ __align__(16) u16 Ks[2 * 4096];   // 2 x (64 key x 64 d), swizzled, rows permuted
  __shared__ __align__(16) u16 Vs[2 * 4096];   // 2 x (64 d x 64 key), swizzled
  const int tid = threadIdx.x;
  const int w = tid >> 6, lane = tid & 63;
  const int fm = lane & 15, fq = lane >> 4;
  const int bid = blockIdx.x;
  int qt, h, half, kbase, nlocal;
  if (NSPLIT == 4) {
    // bid in [0,1024): [qt-desc:4][chunk:2][h:4]; chunks of qt+1 tiles each
    qt = 15 - (bid >> 6);
    half = (bid >> 4) & 3;
    h = bid & 15;
    nlocal = qt + 1;
    kbase = half * nlocal;
  } else {
    // bid in [0,512): complement-paired halves
    const int u = bid & 255, hi = bid >> 8;
    h = u & 15;
    const int qt0 = u >> 4;
    qt = hi ? qt0 : 15 - qt0;
    half = hi;
    nlocal = 2 * qt + 2;
    kbase = half * nlocal;
  }
  const int qb = qt * 256 + w * 32;
  const int dtile = qb >> 6;        // == dtile: partial mask; > dtile: skip

  bf16x8 q0[2], q1[2];
#pragma unroll
  for (int g = 0; g < 2; ++g) {
    const u16* qp = Q + (size_t)(qb + g * 16 + fm) * DM + h * DH + fq * 8;
    q0[g] = *(const bf16x8*)(qp);
    q1[g] = *(const bf16x8*)(qp + 32);
  }
  f32x4 o[2][4];
  f32x4 ls[2];
#pragma unroll
  for (int g = 0; g < 2; ++g) {
#pragma unroll
    for (int r = 0; r < 4; ++r) ls[g][r] = 0.f;
#pragma unroll
    for (int c4 = 0; c4 < 4; ++c4)
#pragma unroll
      for (int r = 0; r < 4; ++r) o[g][c4][r] = 0.f;
  }
  const short ONEB = (short)0x3F80;  // 1.0 bf16
  const bf16x8 vone = {ONEB, ONEB, ONEB, ONEB, ONEB, ONEB, ONEB, ONEB};

  // staging: 512 slots x 16B = one full 64x64 tile; slot = tid.
  // row = tid>>3, stored chunk = tid&7, global chunk = (tid&7) ^ (row&7).
  // K rows permuted: LDS row s holds global key g(s), the 6-bit permutation
  // [b5 b4 b3 b2 b1 b0] -> key bits [b5 | b3 b2 | b4 | b1 b0], which makes
  // st's (t,fq,r) layout coincide with the MFMA B-operand k = fq*8+(t&1)*4+r.
  const int rr = tid >> 3;                 // [0,64)  (LDS row)
  const int cc8 = (tid & 7) ^ (rr & 7);
  const int grr = ((rr >> 5) << 5) | (((rr >> 2) & 3) << 3) | (((rr >> 4) & 1) << 2) | (rr & 3);
  const u16* Kg = K + (size_t)grr * DM + h * DH + cc8 * 8;
  const u16* Vg = Vt + (size_t)(h * DH + rr) * S_LEN + cc8 * 8;
  const int l0 = w * 512;                  // wave-uniform LDS base (u16)
  const int sw7 = fm & 7;
  const f32x4 zf = {0.f, 0.f, 0.f, 0.f};

  glds16(Kg + (size_t)kbase * 64 * DM, Ks + l0);
  glds16(Vg + kbase * 64, Vs + l0);

  int buf = 0;
  for (int kl = 0; kl < nlocal; ++kl) {
    const int ktg = kbase + kl;
    __syncthreads();
    if (kl + 1 < nlocal) {
      int bo = (buf ^ 1) * 4096;
      glds16(Kg + (size_t)(ktg + 1) * 64 * DM, Ks + bo + l0);
      glds16(Vg + (ktg + 1) * 64, Vs + bo + l0);
    }
    if (ktg <= dtile) {
      const u16* Kb = Ks + buf * 4096;
      const u16* Vb = Vs + buf * 4096;

      // S^T = K * Q^T over permuted-staged K rows: st[g][t][r] holds
      // P-logits for key = ktg*64 + (t>>1)*32 + fq*8 + (t&1)*4 + r, q = fm
      f32x4 st[2][4];
#pragma unroll
      for (int t = 0; t < 4; ++t) {
        const u16* kr = Kb + (t * 16 + fm) * 64;
        bf16x8 ka = *(const bf16x8*)(kr + ((fq ^ sw7) * 8));
        bf16x8 kb2 = *(const bf16x8*)(kr + (((fq + 4) ^ sw7) * 8));
#pragma unroll
        for (int g = 0; g < 2; ++g) {
          f32x4 s = __builtin_amdgcn_mfma_f32_16x16x32_bf16(ka, q0[g], zf, 0, 0, 0);
          st[g][t] = __builtin_amdgcn_mfma_f32_16x16x32_bf16(kb2, q1[g], s, 0, 0, 0);
        }
      }
      if (ktg == dtile) {  // diagonal tile: partial causal mask (permuted keys)
#pragma unroll
        for (int g = 0; g < 2; ++g) {
          int qg = qb + g * 16 + fm;
#pragma unroll
          for (int t = 0; t < 4; ++t) {
            int key = ktg * 64 + (t >> 1) * 32 + fq * 8 + (t & 1) * 4;
#pragma unroll
            for (int r = 0; r < 4; ++r)
              st[g][t][r] = (key + r > qg) ? -1e30f : st[g][t][r];
          }
        }
      }
      // V A-operand fragments (unchanged addressing; shared across g)
      bf16x8 pvb[4][2];
#pragma unroll
      for (int c4 = 0; c4 < 4; ++c4) {
        const u16* vr = Vb + (c4 * 16 + fm) * 64;
        pvb[c4][0] = *(const bf16x8*)(vr + ((fq ^ sw7) * 8));
        pvb[c4][1] = *(const bf16x8*)(vr + (((fq + 4) ^ sw7) * 8));
      }
      // register-only softmax+PV: exp2 -> pack -> MFMA (no LDS, no drains)
#pragma unroll
      for (int g = 0; g < 2; ++g) {
        unsigned pw[8];
#pragma unroll
        for (int t = 0; t < 4; ++t) {
          float p0 = __builtin_amdgcn_exp2f(st[g][t][0]);
          float p1 = __builtin_amdgcn_exp2f(st[g][t][1]);
          float p2 = __builtin_amdgcn_exp2f(st[g][t][2]);
          float p3 = __builtin_amdgcn_exp2f(st[g][t][3]);
          pw[t * 2] = pk2t(p0, p1);
          pw[t * 2 + 1] = pk2t(p2, p3);
        }
        uint4 u0 = {pw[0], pw[1], pw[2], pw[3]};
        uint4 u1 = {pw[4], pw[5], pw[6], pw[7]};
        bf16x8 pb0 = __builtin_bit_cast(bf16x8, u0);  // B-frag, keys 0..31 of tile
        bf16x8 pb1 = __builtin_bit_cast(bf16x8, u1);  // B-frag, keys 32..63
        ls[g] = __builtin_amdgcn_mfma_f32_16x16x32_bf16(vone, pb0, ls[g], 0, 0, 0);
        ls[g] = __builtin_amdgcn_mfma_f32_16x16x32_bf16(vone, pb1, ls[g], 0, 0, 0);
#pragma unroll
        for (int c4 = 0; c4 < 4; ++c4) {
          o[g][c4] = __builtin_amdgcn_mfma_f32_16x16x32_bf16(pvb[c4][0], pb0, o[g][c4], 0, 0, 0);
          o[g][c4] = __builtin_amdgcn_mfma_f32_16x16x32_bf16(pvb[c4][1], pb1, o[g][c4], 0, 0, 0);
        }
      }
    }
    buf ^= 1;
  }
  // D layout [d][q]: lane (fm,fq) reg r holds o for q = g*16+fm,
  // d = c4*16 + fq*4 + r. ls[g][*] all hold l[q = g*16+fm].
  if (STORE) {
    // bf16 partials: Opart[half][h][row][d] u16 (RNE), Lpart fp32
    u16* Ob = (u16*)Oacc + (((size_t)half * NH + h) * S_LEN + qt * 256 + w * 32) * DH;
    float* Lb = Lacc + ((size_t)half * NH + h) * S_LEN + qt * 256 + w * 32;
#pragma unroll
    for (int g = 0; g < 2; ++g) {
      if (fq == 0) Lb[g * 16 + fm] = ls[g][0];
#pragma unroll
      for (int c4 = 0; c4 < 4; ++c4) {
        uint2 pv;
        pv.x = pk2(o[g][c4][0], o[g][c4][1]);
        pv.y = pk2(o[g][c4][2], o[g][c4][3]);
        *(uint2*)(Ob + (size_t)(g * 16 + fm) * DH + c4 * 16 + fq * 4) = pv;
      }
    }
  } else {
    // fallback: atomic accumulate into shared fp32 Oacc/Lacc
    float* Ob = (float*)Oacc + ((size_t)h * S_LEN + qt * 256 + w * 32) * DH;
    float* Lb = Lacc + h * S_LEN + qt * 256 + w * 32;
#pragma unroll
    for (int g = 0; g < 2; ++g) {
      if (fq == 0) unsafeAtomicAdd(Lb + g * 16 + fm, ls[g][0]);
#pragma unroll
      for (int c4 = 0; c4 < 4; ++c4)
#pragma unroll
        for (int r = 0; r < 4; ++r)
          unsafeAtomicAdd(Ob + (size_t)(g * 16 + fm) * DH + c4 * 16 + fq * 4 + r, o[g][c4][r]);
    }
  }
}

// ---------------- combine (4-split, bf16 partials) --------------------------
__global__ __launch_bounds__(256) void combine4_kernel(const u16* __restrict__ O,
                                                       const float* __restrict__ L,
                                                       u16* __restrict__ Ctx) {
  int idx = blockIdx.x * 256 + threadIdx.x;  // 1,048,576 threads
  int d4 = (idx & 15) * 4;
  int hh = (idx >> 4) & 15;
  int row = idx >> 8;
  const size_t OS = (size_t)NH * S_LEN * DH, LS = (size_t)NH * S_LEN;
  size_t ob = ((size_t)hh * S_LEN + row) * DH + d4;
  size_t lb = (size_t)hh * S_LEN + row;
  float s0 = 0.f, s1 = 0.f, s2 = 0.f, s3 = 0.f;
#pragma unroll
  for (int s = 0; s < 4; ++s) {
    uint2 v = *(const uint2*)(O + s * OS + ob);
    s0 += b2f(v.x & 0xffffu);
    s1 += b2f(v.x >> 16);
    s2 += b2f(v.y & 0xffffu);
    s3 += b2f(v.y >> 16);
  }
  float il = 1.0f / (L[lb] + L[LS + lb] + L[2 * LS + lb] + L[3 * LS + lb]);
  uint2 o;
  o.x = pk2(s0 * il, s1 * il);
  o.y = pk2(s2 * il, s3 * il);
  *(uint2*)(Ctx + (size_t)row * DM + hh * DH + d4) = o;
}

// ---------------- combine (atomic fallback): Ctx = bf16(Oacc / Lacc) --------
__global__ __launch_bounds__(256) void combine_kernel(const float* __restrict__ Oacc,
                                                      const float* __restrict__ Lacc,
                                                      u16* __restrict__ Ctx) {
  int idx = blockIdx.x * 256 + threadIdx.x;  // 1,048,576 threads
  int d4 = (idx & 15) * 4;
  int hh = (idx >> 4) & 15;
  int row = idx >> 8;
  float4 a = *(const float4*)(Oacc + ((size_t)hh * S_LEN + row) * DH + d4);
  float il = 1.0f / Lacc[hh * S_LEN + row];
  uint2 o;
  o.x = pk2(a.x * il, a.y * il);
  o.y = pk2(a.z * il, a.w * il);
  *(uint2*)(Ctx + (size_t)row * DM + hh * DH + d4) = o;
}

extern "C" void kernel_launch(void* const* d_in, const int* in_sizes, int n_in,
                              void* d_out, int out_size, void* d_ws, size_t ws_size,
                              hipStream_t stream) {
  const float* x  = (const float*)d_in[0];
  const float* Wq = (const float*)d_in[1];
  const float* Wk = (const float*)d_in[2];
  const float* Wv = (const float*)d_in[3];
  const float* Wo = (const float*)d_in[4];
  float* out = (float*)d_out;

  const size_t MB = 1u << 20;
  char* ws = (char*)d_ws;

  if (ws_size >= 72 * MB) {
    // 4-split bf16-partial layout (72 MB):
    //  [0,8)   xb -> Ctx;  [8,14) wqb/wkb/wvb -> Lpart[4] fp32 (1 MB)
    //  [14,16) wob; [16,40) Qb, Kb, Vtb; [40,72) Opart [4][16][4096][64] bf16
    u16* xb    = (u16*)(ws + 0 * MB);
    u16* wqb   = (u16*)(ws + 8 * MB);
    u16* wkb   = (u16*)(ws + 10 * MB);
    u16* wvb   = (u16*)(ws + 12 * MB);
    u16* wob   = (u16*)(ws + 14 * MB);
    u16* Qb    = (u16*)(ws + 16 * MB);
    u16* Kb    = (u16*)(ws + 24 * MB);
    u16* Vtb   = (u16*)(ws + 32 * MB);
    u16* Op    = (u16*)(ws + 40 * MB);
    float* Lp  = (float*)(ws + 8 * MB);
    u16* Ctx   = (u16*)(ws + 0 * MB);

    cvt_all<<<8192, 256, 0, stream>>>(x, Wq, Wk, Wv, Wo, xb, wqb, wkb, wvb, wob);
    qkv_gemm<<<dim3(24, 32), 512, 0, stream>>>(xb, wqb, wkb, wvb, Qb, Kb, Vtb);
    attn_kernel<1, 4><<<1024, 512, 0, stream>>>(Qb, Kb, Vtb, Op, Lp);
    combine4_kernel<<<4096, 256, 0, stream>>>(Op, Lp, Ctx);
    o_gemm<<<dim3(8, 64), 256, 0, stream>>>(Ctx, wob, out, S_LEN, DM, DM);
  } else {
    // fallback: round-0 layout + atomic path
    u16* xb    = (u16*)(ws + 0 * MB);
    u16* wqb   = (u16*)(ws + 8 * MB);
    u16* wkb   = (u16*)(ws + 10 * MB);
    u16* wvb   = (u16*)(ws + 12 * MB);
    float* Oacc = (float*)(ws + 0 * MB);
    float* Lacc = (float*)(ws + 16 * MB);
    u16* wob   = (u16*)(ws + 17 * MB);
    u16* Qb    = (u16*)(ws + 19 * MB);
    u16* Kb    = (u16*)(ws + 27 * MB);
    u16* Vtb   = (u16*)(ws + 35 * MB);
    u16* Ctx   = (u16*)(ws + 43 * MB);

    cvt_all<<<8192, 256, 0, stream>>>(x, Wq, Wk, Wv, Wo, xb, wqb, wkb, wvb, wob);
    qkv_gemm<<<dim3(24, 32), 512, 0, stream>>>(xb, wqb, wkb, wvb, Qb, Kb, Vtb);
    zero_kernel<<<4160, 256, 0, stream>>>((float4*)Oacc);
    attn_kernel<0, 2><<<512, 512, 0, stream>>>(Qb, Kb, Vtb, Oacc, Lacc);
    combine_kernel<<<4096, 256, 0, stream>>>(Oacc, Lacc, Ctx);
    o_gemm<<<dim3(8, 64), 256, 0, stream>>>(Ctx, wob, out, S_LEN, DM, DM);
  }
}

// Round 19
// 186.497 us; speedup vs baseline: 1.4770x; 1.0040x over previous
//
#include <hip/hip_runtime.h>
#include <hip/hip_bf16.h>

typedef __attribute__((ext_vector_type(8))) short bf16x8;
typedef __attribute__((ext_vector_type(4))) float f32x4;
typedef unsigned short u16;

#define S_LEN 4096
#define DM 1024
#define NH 16
#define DH 64

// manual RNE fp32->bf16 (inputs never NaN here): 3 VALU ops
__device__ __forceinline__ u16 f2b_rne(float f) {
  unsigned u = __builtin_bit_cast(unsigned, f);
  return (u16)((u + 0x7fffu + ((u >> 16) & 1u)) >> 16);
}
// pack two fp32 -> bf16x2 in one u32 (RNE)
__device__ __forceinline__ unsigned pk2(float a, float b) {
  unsigned ua = __builtin_bit_cast(unsigned, a);
  unsigned ub = __builtin_bit_cast(unsigned, b);
  ua = (ua + 0x7fffu + ((ua >> 16) & 1u)) >> 16;
  ub = (ub + 0x7fffu + ((ub >> 16) & 1u)) & 0xffff0000u;
  return ua | ub;
}
// pack two fp32 -> bf16x2, TRUNCATED: single v_perm_b32 (low=a, high=b).
// bias cancels in softmax (same P in numerator and denominator).
__device__ __forceinline__ unsigned pk2t(float a, float b) {
  return __builtin_amdgcn_perm(__builtin_bit_cast(unsigned, b),
                               __builtin_bit_cast(unsigned, a), 0x07060302u);
}
// bf16 (u16) -> f32
__device__ __forceinline__ float b2f(unsigned u) {
  return __builtin_bit_cast(float, u << 16);
}

// global -> LDS direct (16B per lane; lds base must be wave-uniform)
__device__ __forceinline__ void glds16(const u16* g, u16* l) {
  __builtin_amdgcn_global_load_lds(
      (const __attribute__((address_space(1))) unsigned int*)g,
      (__attribute__((address_space(3))) unsigned int*)l, 16, 0, 0);
}

// ---------------- fp32 -> bf16, all 5 inputs in one launch ----------------
__global__ __launch_bounds__(256) void cvt_all(const float* __restrict__ x,
                                               const float* __restrict__ Wq,
                                               const float* __restrict__ Wk,
                                               const float* __restrict__ Wv,
                                               const float* __restrict__ Wo,
                                               u16* __restrict__ xb, u16* __restrict__ wqb,
                                               u16* __restrict__ wkb, u16* __restrict__ wvb,
                                               u16* __restrict__ wob) {
  int idx = (blockIdx.x * 256 + threadIdx.x) * 4;
  const float* src;
  u16* dst;
  int o;
  if (idx < 4194304) {
    src = x; dst = xb; o = idx;
  } else {
    int t = idx - 4194304;
    int wsel = t >> 20;
    o = t & 1048575;
    src = (wsel == 0) ? Wq : (wsel == 1) ? Wk : (wsel == 2) ? Wv : Wo;
    dst = (wsel == 0) ? wqb : (wsel == 1) ? wkb : (wsel == 2) ? wvb : wob;
  }
  float4 v = *(const float4*)(src + o);
  uint2 ov;
  ov.x = pk2(v.x, v.y);
  ov.y = pk2(v.z, v.w);
  *(uint2*)(dst + o) = ov;
}

// ---------------- zero the O/L accumulators (fallback path only) -----------
__global__ __launch_bounds__(256) void zero_kernel(float4* __restrict__ p) {
  p[blockIdx.x * 256 + threadIdx.x] = float4{0.f, 0.f, 0.f, 0.f};
}

// ---------------- fused QKV NT-GEMM with RoPE epilogue; V written transposed
// v2: 512 threads, 8 waves (4 row-groups x 2 col-groups), same 128x128 tile.
// grid (24, 32): mat = bx>>3 (0=Q rope+scale, 1=K rope, 2=V -> Vt), nb = (bx&7)*128
__global__ __launch_bounds__(512) void qkv_gemm(const u16* __restrict__ A,
                                                const u16* __restrict__ Wq,
                                                const u16* __restrict__ Wk,
                                                const u16* __restrict__ Wv,
                                                u16* __restrict__ Qo, u16* __restrict__ Ko,
                                                u16* __restrict__ Vt) {
  __shared__ __align__(16) u16 As[2 * 128 * 32];
  __shared__ __align__(16) u16 Bs[2 * 128 * 32];
  const int mat = blockIdx.x >> 3;
  const u16* B = (mat == 0) ? Wq : (mat == 1) ? Wk : Wv;
  const int K = DM, N = DM;
  const int tid = threadIdx.x;
  const int wave = tid >> 6, lane = tid & 63;
  const int fm = lane & 15, fq = lane >> 4;
  const int mb = blockIdx.y * 128, nb = (blockIdx.x & 7) * 128;
  const int wm = (wave & 3) * 32, wn = (wave >> 2) * 64;

  f32x4 acc[2][4];
#pragma unroll
  for (int i = 0; i < 2; ++i)
#pragma unroll
    for (int j = 0; j < 4; ++j)
#pragma unroll
      for (int r = 0; r < 4; ++r) acc[i][j][r] = 0.f;

  // staging: 512 threads x 16B = one full 128x32 tile per array.
  const int r_ = tid >> 2;
  const int cg = (tid & 3) ^ ((r_ >> 1) & 3);
  const u16* Ag0 = A + (size_t)(mb + r_) * K + cg * 8;
  const u16* Bg0 = B + (size_t)(nb + r_) * K + cg * 8;
  const int l0 = wave * 512;   // 8 waves x 512 u16 = 4096 u16 tile
  const int sw = (fm >> 1) & 3;

  int buf = 0;
  glds16(Ag0, As + l0);
  glds16(Bg0, Bs + l0);

  for (int k0 = 0; k0 < K; k0 += 32) {
    __syncthreads();
    if (k0 + 32 < K) {
      int bo = (buf ^ 1) * 4096;
      glds16(Ag0 + k0 + 32, As + bo + l0);
      glds16(Bg0 + k0 + 32, Bs + bo + l0);
    }
    const u16* Ab = As + buf * 4096;
    const u16* Bb = Bs + buf * 4096;
    bf16x8 av[2], bv[4];
#pragma unroll
    for (int t = 0; t < 2; ++t)
      av[t] = *(const bf16x8*)(Ab + (wm + t * 16 + fm) * 32 + ((fq ^ sw) * 8));
#pragma unroll
    for (int t = 0; t < 4; ++t)
      bv[t] = *(const bf16x8*)(Bb + (wn + t * 16 + fm) * 32 + ((fq ^ sw) * 8));
#pragma unroll
    for (int i = 0; i < 2; ++i)
#pragma unroll
      for (int j = 0; j < 4; ++j)
        acc[i][j] = __builtin_amdgcn_mfma_f32_16x16x32_bf16(av[i], bv[j], acc[i][j], 0, 0, 0);
    buf ^= 1;
  }

  if (mat < 2) {
    // RoPE epilogue (in-register): pairs (d, d+32) = regs (j, j+2), d = j*16+fm, j in {0,1}
    u16* Out = (mat == 0) ? Qo : Ko;
    const float qs = (mat == 0) ? 0.1803368801111204f : 1.0f;  // 0.125*log2(e) for Q
    const float c1 = -9.2103403719761836f / 32.f;              // -ln(10000)/32
    const float if0 = __expf((float)fm * c1);
    const float if1 = __expf((float)(16 + fm) * c1);
#pragma unroll
    for (int ii = 0; ii < 2; ++ii) {
#pragma unroll
      for (int r = 0; r < 4; ++r) {
        float s = (float)(mb + wm + ii * 16 + fq * 4 + r);
#pragma unroll
        for (int jp = 0; jp < 2; ++jp) {
          float ang = s * (jp ? if1 : if0);
          float sn, cs;
          __sincosf(ang, &sn, &cs);
          float a = acc[ii][jp][r], b = acc[ii][jp + 2][r];
          acc[ii][jp][r] = (a * cs - b * sn) * qs;
          acc[ii][jp + 2][r] = (b * cs + a * sn) * qs;
        }
      }
    }
#pragma unroll
    for (int i = 0; i < 2; ++i)
#pragma unroll
      for (int j = 0; j < 4; ++j)
#pragma unroll
        for (int r = 0; r < 4; ++r) {
          int row = mb + wm + i * 16 + fq * 4 + r;
          int col = nb + wn + j * 16 + fm;
          Out[(size_t)row * N + col] = f2b_rne(acc[i][j][r]);
        }
  } else {
    // V: write transposed Vt[col][row]; 4 r-values are contiguous rows -> 8B store
#pragma unroll
    for (int i = 0; i < 2; ++i)
#pragma unroll
      for (int j = 0; j < 4; ++j) {
        int col = nb + wn + j * 16 + fm;
        int row0 = mb + wm + i * 16 + fq * 4;
        uint2 pv;
        pv.x = pk2(acc[i][j][0], acc[i][j][1]);
        pv.y = pk2(acc[i][j][2], acc[i][j][3]);
        *(uint2*)(Vt + (size_t)col * S_LEN + row0) = pv;
      }
  }
}

// ---------------- O-projection NT GEMM, 64x128 tiles (fp32 out) -------------
// v2: 512 threads, 8 waves (2 row x 4 col, 32x32 out each), same 64x128
// tile. Old 256-thread version: grid 512 x 4 waves = 8 waves/CU (25%
// ceiling), latency-bound — same signature qkv had. 8-wave blocks -> 16
// waves/CU. B's 128x32 tile = one 512-thread glds16; A's 64x32 staged by
// waves 0-3 (wave-uniform predicate). grid (8, 64).
__global__ __launch_bounds__(512) void o_gemm(const u16* __restrict__ A,
                                              const u16* __restrict__ B,
                                              float* __restrict__ C, int M, int N, int K) {
  __shared__ __align__(16) u16 As[2 * 64 * 32];
  __shared__ __align__(16) u16 Bs[2 * 128 * 32];
  const int tid = threadIdx.x;
  const int wave = tid >> 6, lane = tid & 63;
  const int fm = lane & 15, fq = lane >> 4;
  const int mb = blockIdx.y * 64, nb = blockIdx.x * 128;
  const int wm = (wave & 1) * 32, wn = (wave >> 1) * 32;

  f32x4 acc[2][2];
#pragma unroll
  for (int i = 0; i < 2; ++i)
#pragma unroll
    for (int j = 0; j < 2; ++j)
#pragma unroll
      for (int r = 0; r < 4; ++r) acc[i][j][r] = 0.f;

  const int r_ = tid >> 2;                     // [0,128)
  const int cg = (tid & 3) ^ ((r_ >> 1) & 3);
  const u16* Ag0 = A + (size_t)(mb + r_) * K + cg * 8;   // valid for tid<256
  const u16* Bg0 = B + (size_t)(nb + r_) * K + cg * 8;
  const int l0 = wave * 512;
  const int sw = (fm >> 1) & 3;

  int buf = 0;
  if (wave < 4) glds16(Ag0, As + l0);
  glds16(Bg0, Bs + l0);

  for (int k0 = 0; k0 < K; k0 += 32) {
    __syncthreads();
    if (k0 + 32 < K) {
      int aoff = (buf ^ 1) * 2048, boff = (buf ^ 1) * 4096;
      if (wave < 4) glds16(Ag0 + k0 + 32, As + aoff + l0);
      glds16(Bg0 + k0 + 32, Bs + boff + l0);
    }
    const u16* Ab = As + buf * 2048;
    const u16* Bb = Bs + buf * 4096;
    bf16x8 av[2], bv[2];
#pragma unroll
    for (int t = 0; t < 2; ++t)
      av[t] = *(const bf16x8*)(Ab + (wm + t * 16 + fm) * 32 + ((fq ^ sw) * 8));
#pragma unroll
    for (int t = 0; t < 2; ++t)
      bv[t] = *(const bf16x8*)(Bb + (wn + t * 16 + fm) * 32 + ((fq ^ sw) * 8));
#pragma unroll
    for (int i = 0; i < 2; ++i)
#pragma unroll
      for (int j = 0; j < 2; ++j)
        acc[i][j] = __builtin_amdgcn_mfma_f32_16x16x32_bf16(av[i], bv[j], acc[i][j], 0, 0, 0);
    buf ^= 1;
  }
#pragma unroll
  for (int i = 0; i < 2; ++i)
#pragma unroll
    for (int j = 0; j < 2; ++j)
#pragma unroll
      for (int r = 0; r < 4; ++r) {
        int row = mb + wm + i * 16 + fq * 4 + r;
        int col = nb + wn + j * 16 + fm;
        C[(size_t)row * N + col] = acc[i][j][r];
      }
}

// ---------------- causal flash attention v20: v17 + bf16 partials ----------
// Best-measured configuration (round 17/18: ~46.4 us attn). Reg-only softmax
// via permuted K staging (0 bank conflicts), 512 threads, 8 waves x 32
// q-rows, NSPLIT=4 chunks of qt+1 tiles, grid 1024 longest-first, bf16
// O-partials. V staging in LDS is load-bearing (V-from-L2 refuted twice).
template <int STORE, int NSPLIT>
__global__ __launch_bounds__(512, 4) void attn_kernel(const u16* __restrict__ Q,
                                                      const u16* __restrict__ K,
                                                      const u16* __restrict__ Vt,
                                                      void* __restrict__ Oacc,
                                                      float* __restrict__ Lacc) {
  __shared__ __align__(16) u16 Ks[2 * 4096];   // 2 x (64 key x 64 d), swizzled, rows permuted
  __shared__ __align__(16) u16 Vs[2 * 4096];   // 2 x (64 d x 64 key), swizzled
  const int tid = threadIdx.x;
  const int w = tid >> 6, lane = tid & 63;
  const int fm = lane & 15, fq = lane >> 4;
  const int bid = blockIdx.x;
  int qt, h, half, kbase, nlocal;
  if (NSPLIT == 4) {
    // bid in [0,1024): [qt-desc:4][chunk:2][h:4]; chunks of qt+1 tiles each
    qt = 15 - (bid >> 6);
    half = (bid >> 4) & 3;
    h = bid & 15;
    nlocal = qt + 1;
    kbase = half * nlocal;
  } else {
    // bid in [0,512): complement-paired halves
    const int u = bid & 255, hi = bid >> 8;
    h = u & 15;
    const int qt0 = u >> 4;
    qt = hi ? qt0 : 15 - qt0;
    half = hi;
    nlocal = 2 * qt + 2;
    kbase = half * nlocal;
  }
  const int qb = qt * 256 + w * 32;
  const int dtile = qb >> 6;        // == dtile: partial mask; > dtile: skip

  bf16x8 q0[2], q1[2];
#pragma unroll
  for (int g = 0; g < 2; ++g) {
    const u16* qp = Q + (size_t)(qb + g * 16 + fm) * DM + h * DH + fq * 8;
    q0[g] = *(const bf16x8*)(qp);
    q1[g] = *(const bf16x8*)(qp + 32);
  }
  f32x4 o[2][4];
  f32x4 ls[2];
#pragma unroll
  for (int g = 0; g < 2; ++g) {
#pragma unroll
    for (int r = 0; r < 4; ++r) ls[g][r] = 0.f;
#pragma unroll
    for (int c4 = 0; c4 < 4; ++c4)
#pragma unroll
      for (int r = 0; r < 4; ++r) o[g][c4][r] = 0.f;
  }
  const short ONEB = (short)0x3F80;  // 1.0 bf16
  const bf16x8 vone = {ONEB, ONEB, ONEB, ONEB, ONEB, ONEB, ONEB, ONEB};

  // staging: 512 slots x 16B = one full 64x64 tile; slot = tid.
  // row = tid>>3, stored chunk = tid&7, global chunk = (tid&7) ^ (row&7).
  // K rows permuted: LDS row s holds global key g(s), the 6-bit permutation
  // [b5 b4 b3 b2 b1 b0] -> key bits [b5 | b3 b2 | b4 | b1 b0], which makes
  // st's (t,fq,r) layout coincide with the MFMA B-operand k = fq*8+(t&1)*4+r.
  const int rr = tid >> 3;                 // [0,64)  (LDS row)
  const int cc8 = (tid & 7) ^ (rr & 7);
  const int grr = ((rr >> 5) << 5) | (((rr >> 2) & 3) << 3) | (((rr >> 4) & 1) << 2) | (rr & 3);
  const u16* Kg = K + (size_t)grr * DM + h * DH + cc8 * 8;
  const u16* Vg = Vt + (size_t)(h * DH + rr) * S_LEN + cc8 * 8;
  const int l0 = w * 512;                  // wave-uniform LDS base (u16)
  const int sw7 = fm & 7;
  const f32x4 zf = {0.f, 0.f, 0.f, 0.f};

  glds16(Kg + (size_t)kbase * 64 * DM, Ks + l0);
  glds16(Vg + kbase * 64, Vs + l0);

  int buf = 0;
  for (int kl = 0; kl < nlocal; ++kl) {
    const int ktg = kbase + kl;
    __syncthreads();
    if (kl + 1 < nlocal) {
      int bo = (buf ^ 1) * 4096;
      glds16(Kg + (size_t)(ktg + 1) * 64 * DM, Ks + bo + l0);
      glds16(Vg + (ktg + 1) * 64, Vs + bo + l0);
    }
    if (ktg <= dtile) {
      const u16* Kb = Ks + buf * 4096;
      const u16* Vb = Vs + buf * 4096;

      // S^T = K * Q^T over permuted-staged K rows: st[g][t][r] holds
      // P-logits for key = ktg*64 + (t>>1)*32 + fq*8 + (t&1)*4 + r, q = fm
      f32x4 st[2][4];
#pragma unroll
      for (int t = 0; t < 4; ++t) {
        const u16* kr = Kb + (t * 16 + fm) * 64;
        bf16x8 ka = *(const bf16x8*)(kr + ((fq ^ sw7) * 8));
        bf16x8 kb2 = *(const bf16x8*)(kr + (((fq + 4) ^ sw7) * 8));
#pragma unroll
        for (int g = 0; g < 2; ++g) {
          f32x4 s = __builtin_amdgcn_mfma_f32_16x16x32_bf16(ka, q0[g], zf, 0, 0, 0);
          st[g][t] = __builtin_amdgcn_mfma_f32_16x16x32_bf16(kb2, q1[g], s, 0, 0, 0);
        }
      }
      if (ktg == dtile) {  // diagonal tile: partial causal mask (permuted keys)
#pragma unroll
        for (int g = 0; g < 2; ++g) {
          int qg = qb + g * 16 + fm;
#pragma unroll
          for (int t = 0; t < 4; ++t) {
            int key = ktg * 64 + (t >> 1) * 32 + fq * 8 + (t & 1) * 4;
#pragma unroll
            for (int r = 0; r < 4; ++r)
              st[g][t][r] = (key + r > qg) ? -1e30f : st[g][t][r];
          }
        }
      }
      // V A-operand fragments (unchanged addressing; shared across g)
      bf16x8 pvb[4][2];
#pragma unroll
      for (int c4 = 0; c4 < 4; ++c4) {
        const u16* vr = Vb + (c4 * 16 + fm) * 64;
        pvb[c4][0] = *(const bf16x8*)(vr + ((fq ^ sw7) * 8));
        pvb[c4][1] = *(const bf16x8*)(vr + (((fq + 4) ^ sw7) * 8));
      }
      // register-only softmax+PV: exp2 -> pack -> MFMA (no LDS, no drains)
#pragma unroll
      for (int g = 0; g < 2; ++g) {
        unsigned pw[8];
#pragma unroll
        for (int t = 0; t < 4; ++t) {
          float p0 = __builtin_amdgcn_exp2f(st[g][t][0]);
          float p1 = __builtin_amdgcn_exp2f(st[g][t][1]);
          float p2 = __builtin_amdgcn_exp2f(st[g][t][2]);
          float p3 = __builtin_amdgcn_exp2f(st[g][t][3]);
          pw[t * 2] = pk2t(p0, p1);
          pw[t * 2 + 1] = pk2t(p2, p3);
        }
        uint4 u0 = {pw[0], pw[1], pw[2], pw[3]};
        uint4 u1 = {pw[4], pw[5], pw[6], pw[7]};
        bf16x8 pb0 = __builtin_bit_cast(bf16x8, u0);  // B-frag, keys 0..31 of tile
        bf16x8 pb1 = __builtin_bit_cast(bf16x8, u1);  // B-frag, keys 32..63
        ls[g] = __builtin_amdgcn_mfma_f32_16x16x32_bf16(vone, pb0, ls[g], 0, 0, 0);
        ls[g] = __builtin_amdgcn_mfma_f32_16x16x32_bf16(vone, pb1, ls[g], 0, 0, 0);
#pragma unroll
        for (int c4 = 0; c4 < 4; ++c4) {
          o[g][c4] = __builtin_amdgcn_mfma_f32_16x16x32_bf16(pvb[c4][0], pb0, o[g][c4], 0, 0, 0);
          o[g][c4] = __builtin_amdgcn_mfma_f32_16x16x32_bf16(pvb[c4][1], pb1, o[g][c4], 0, 0, 0);
        }
      }
    }
    buf ^= 1;
  }
  // D layout [d][q]: lane (fm,fq) reg r holds o for q = g*16+fm,
  // d = c4*16 + fq*4 + r. ls[g][*] all hold l[q = g*16+fm].
  if (STORE) {
    // bf16 partials: Opart[half][h][row][d] u16 (RNE), Lpart fp32
    u16* Ob = (u16*)Oacc + (((size_t)half * NH + h) * S_LEN + qt * 256 + w * 32) * DH;
    float* Lb = Lacc + ((size_t)half * NH + h) * S_LEN + qt * 256 + w * 32;
#pragma unroll
    for (int g = 0; g < 2; ++g) {
      if (fq == 0) Lb[g * 16 + fm] = ls[g][0];
#pragma unroll
      for (int c4 = 0; c4 < 4; ++c4) {
        uint2 pv;
        pv.x = pk2(o[g][c4][0], o[g][c4][1]);
        pv.y = pk2(o[g][c4][2], o[g][c4][3]);
        *(uint2*)(Ob + (size_t)(g * 16 + fm) * DH + c4 * 16 + fq * 4) = pv;
      }
    }
  } else {
    // fallback: atomic accumulate into shared fp32 Oacc/Lacc
    float* Ob = (float*)Oacc + ((size_t)h * S_LEN + qt * 256 + w * 32) * DH;
    float* Lb = Lacc + h * S_LEN + qt * 256 + w * 32;
#pragma unroll
    for (int g = 0; g < 2; ++g) {
      if (fq == 0) unsafeAtomicAdd(Lb + g * 16 + fm, ls[g][0]);
#pragma unroll
      for (int c4 = 0; c4 < 4; ++c4)
#pragma unroll
        for (int r = 0; r < 4; ++r)
          unsafeAtomicAdd(Ob + (size_t)(g * 16 + fm) * DH + c4 * 16 + fq * 4 + r, o[g][c4][r]);
    }
  }
}

// ---------------- combine (4-split, bf16 partials) --------------------------
__global__ __launch_bounds__(256) void combine4_kernel(const u16* __restrict__ O,
                                                       const float* __restrict__ L,
                                                       u16* __restrict__ Ctx) {
  int idx = blockIdx.x * 256 + threadIdx.x;  // 1,048,576 threads
  int d4 = (idx & 15) * 4;
  int hh = (idx >> 4) & 15;
  int row = idx >> 8;
  const size_t OS = (size_t)NH * S_LEN * DH, LS = (size_t)NH * S_LEN;
  size_t ob = ((size_t)hh * S_LEN + row) * DH + d4;
  size_t lb = (size_t)hh * S_LEN + row;
  float s0 = 0.f, s1 = 0.f, s2 = 0.f, s3 = 0.f;
#pragma unroll
  for (int s = 0; s < 4; ++s) {
    uint2 v = *(const uint2*)(O + s * OS + ob);
    s0 += b2f(v.x & 0xffffu);
    s1 += b2f(v.x >> 16);
    s2 += b2f(v.y & 0xffffu);
    s3 += b2f(v.y >> 16);
  }
  float il = 1.0f / (L[lb] + L[LS + lb] + L[2 * LS + lb] + L[3 * LS + lb]);
  uint2 o;
  o.x = pk2(s0 * il, s1 * il);
  o.y = pk2(s2 * il, s3 * il);
  *(uint2*)(Ctx + (size_t)row * DM + hh * DH + d4) = o;
}

// ---------------- combine (atomic fallback): Ctx = bf16(Oacc / Lacc) --------
__global__ __launch_bounds__(256) void combine_kernel(const float* __restrict__ Oacc,
                                                      const float* __restrict__ Lacc,
                                                      u16* __restrict__ Ctx) {
  int idx = blockIdx.x * 256 + threadIdx.x;  // 1,048,576 threads
  int d4 = (idx & 15) * 4;
  int hh = (idx >> 4) & 15;
  int row = idx >> 8;
  float4 a = *(const float4*)(Oacc + ((size_t)hh * S_LEN + row) * DH + d4);
  float il = 1.0f / Lacc[hh * S_LEN + row];
  uint2 o;
  o.x = pk2(a.x * il, a.y * il);
  o.y = pk2(a.z * il, a.w * il);
  *(uint2*)(Ctx + (size_t)row * DM + hh * DH + d4) = o;
}

extern "C" void kernel_launch(void* const* d_in, const int* in_sizes, int n_in,
                              void* d_out, int out_size, void* d_ws, size_t ws_size,
                              hipStream_t stream) {
  const float* x  = (const float*)d_in[0];
  const float* Wq = (const float*)d_in[1];
  const float* Wk = (const float*)d_in[2];
  const float* Wv = (const float*)d_in[3];
  const float* Wo = (const float*)d_in[4];
  float* out = (float*)d_out;

  const size_t MB = 1u << 20;
  char* ws = (char*)d_ws;

  if (ws_size >= 72 * MB) {
    // 4-split bf16-partial layout (72 MB):
    //  [0,8)   xb -> Ctx;  [8,14) wqb/wkb/wvb -> Lpart[4] fp32 (1 MB)
    //  [14,16) wob; [16,40) Qb, Kb, Vtb; [40,72) Opart [4][16][4096][64] bf16
    u16* xb    = (u16*)(ws + 0 * MB);
    u16* wqb   = (u16*)(ws + 8 * MB);
    u16* wkb   = (u16*)(ws + 10 * MB);
    u16* wvb   = (u16*)(ws + 12 * MB);
    u16* wob   = (u16*)(ws + 14 * MB);
    u16* Qb    = (u16*)(ws + 16 * MB);
    u16* Kb    = (u16*)(ws + 24 * MB);
    u16* Vtb   = (u16*)(ws + 32 * MB);
    u16* Op    = (u16*)(ws + 40 * MB);
    float* Lp  = (float*)(ws + 8 * MB);
    u16* Ctx   = (u16*)(ws + 0 * MB);

    cvt_all<<<8192, 256, 0, stream>>>(x, Wq, Wk, Wv, Wo, xb, wqb, wkb, wvb, wob);
    qkv_gemm<<<dim3(24, 32), 512, 0, stream>>>(xb, wqb, wkb, wvb, Qb, Kb, Vtb);
    attn_kernel<1, 4><<<1024, 512, 0, stream>>>(Qb, Kb, Vtb, Op, Lp);
    combine4_kernel<<<4096, 256, 0, stream>>>(Op, Lp, Ctx);
    o_gemm<<<dim3(8, 64), 512, 0, stream>>>(Ctx, wob, out, S_LEN, DM, DM);
  } else {
    // fallback: round-0 layout + atomic path
    u16* xb    = (u16*)(ws + 0 * MB);
    u16* wqb   = (u16*)(ws + 8 * MB);
    u16* wkb   = (u16*)(ws + 10 * MB);
    u16* wvb   = (u16*)(ws + 12 * MB);
    float* Oacc = (float*)(ws + 0 * MB);
    float* Lacc = (float*)(ws + 16 * MB);
    u16* wob   = (u16*)(ws + 17 * MB);
    u16* Qb    = (u16*)(ws + 19 * MB);
    u16* Kb    = (u16*)(ws + 27 * MB);
    u16* Vtb   = (u16*)(ws + 35 * MB);
    u16* Ctx   = (u16*)(ws + 43 * MB);

    cvt_all<<<8192, 256, 0, stream>>>(x, Wq, Wk, Wv, Wo, xb, wqb, wkb, wvb, wob);
    qkv_gemm<<<dim3(24, 32), 512, 0, stream>>>(xb, wqb, wkb, wvb, Qb, Kb, Vtb);
    zero_kernel<<<4160, 256, 0, stream>>>((float4*)Oacc);
    attn_kernel<0, 2><<<512, 512, 0, stream>>>(Qb, Kb, Vtb, Oacc, Lacc);
    combine_kernel<<<4096, 256, 0, stream>>>(Oacc, Lacc, Ctx);
    o_gemm<<<dim3(8, 64), 512, 0, stream>>>(Ctx, wob, out, S_LEN, DM, DM);
  }
}